// Round 17
// baseline (463.097 us; speedup 1.0000x reference)
//
#include <hip/hip_runtime.h>
#include <math.h>

#define QK_SCALE 0.14433756729740643f   // 1/sqrt(3*16)
#define BB_SCALE 0.57735026918962576f   // 1/sqrt(3)
#define HW_COEF  0.13608276348795434f   // 1/sqrt(54)

// part layout per (row,jc8), stride 1600 floats:
// [0:12] s_sum, [12:1548] o_pair partial (h*128+c)
#define PART_STRIDE 1600

// ---------------------------------------------------------------------------
// K_PROJ: tiled GEMM (1024x384)@(384x1152 composite) with scatter epilogue.
// ---------------------------------------------------------------------------
__global__ __launch_bounds__(256) void k_proj(
    const float* __restrict__ s,
    const float* __restrict__ wq,  const float* __restrict__ bq,
    const float* __restrict__ wkv, const float* __restrict__ bkv,
    const float* __restrict__ wqp, const float* __restrict__ bqp,
    const float* __restrict__ wkvp,const float* __restrict__ bkvp,
    float* __restrict__ q_o,    // (B,N,192)
    float* __restrict__ kT2,    // (B,12,512,16)
    float* __restrict__ vT,     // (B,12,16,512)
    float* __restrict__ qpl,    // (B,N,48,3) local
    float* __restrict__ kvpl)   // (B,N,144,3) local
{
    __shared__ __align__(16) float A_t[64 * 36];
    __shared__ __align__(16) float W_s[64 * 132];
    const int row0 = blockIdx.x * 32;
    const int C0 = blockIdx.y * 128;
    const int t = threadIdx.x;
    const int cq = t & 31, rq = t >> 5;
    float acc[4][4] = {};
    for (int ch = 0; ch < 6; ++ch) {
        const int k0 = ch * 64;
        __syncthreads();
        for (int idx = t; idx < 512; idx += 256) {
            int r = idx & 31, kq = idx >> 5;
            float4 a = *(const float4*)&s[(size_t)(row0 + r) * 384 + k0 + kq * 4];
            A_t[(kq * 4 + 0) * 36 + r] = a.x;
            A_t[(kq * 4 + 1) * 36 + r] = a.y;
            A_t[(kq * 4 + 2) * 36 + r] = a.z;
            A_t[(kq * 4 + 3) * 36 + r] = a.w;
        }
        for (int idx = t; idx < 2048; idx += 256) {
            int kk = idx >> 5, c4 = idx & 31;
            int C4 = C0 + c4 * 4;
            const float* w; int sub, wcols;
            if (C4 < 192)      { w = wq;   sub = C4;       wcols = 192; }
            else if (C4 < 576) { w = wkv;  sub = C4 - 192; wcols = 384; }
            else if (C4 < 720) { w = wqp;  sub = C4 - 576; wcols = 144; }
            else               { w = wkvp; sub = C4 - 720; wcols = 432; }
            *(float4*)&W_s[kk * 132 + c4 * 4] =
                *(const float4*)&w[(size_t)(k0 + kk) * wcols + sub];
        }
        __syncthreads();
        #pragma unroll 8
        for (int kk = 0; kk < 64; ++kk) {
            float4 a4 = *(const float4*)&A_t[kk * 36 + rq * 4];
            float4 w4 = *(const float4*)&W_s[kk * 132 + cq * 4];
            acc[0][0] += a4.x * w4.x; acc[0][1] += a4.x * w4.y; acc[0][2] += a4.x * w4.z; acc[0][3] += a4.x * w4.w;
            acc[1][0] += a4.y * w4.x; acc[1][1] += a4.y * w4.y; acc[1][2] += a4.y * w4.z; acc[1][3] += a4.y * w4.w;
            acc[2][0] += a4.z * w4.x; acc[2][1] += a4.z * w4.y; acc[2][2] += a4.z * w4.z; acc[2][3] += a4.z * w4.w;
            acc[3][0] += a4.w * w4.x; acc[3][1] += a4.w * w4.y; acc[3][2] += a4.w * w4.z; acc[3][3] += a4.w * w4.w;
        }
    }
    #pragma unroll
    for (int r = 0; r < 4; ++r) {
        int row = row0 + rq * 4 + r;
        int b = row >> 9, n = row & 511;
        #pragma unroll
        for (int u = 0; u < 4; ++u) {
            int col = C0 + cq * 4 + u;
            float v = acc[r][u];
            if (col < 192) {
                q_o[(size_t)row * 192 + col] = v + bq[col];
            } else if (col < 576) {
                int sub = col - 192;
                v += bkv[sub];
                int h = sub >> 5, rr = sub & 31;
                if (rr < 16) kT2[((size_t)((b * 12 + h) << 9) + n) * 16 + rr] = v;
                else         vT[(((b * 12 + h) * 16 + (rr - 16)) << 9) + n] = v;
            } else if (col < 720) {
                int sub = col - 576;
                v += bqp[sub];
                int axis = sub / 48, rem = sub % 48;
                qpl[(size_t)row * 144 + rem * 3 + axis] = v;
            } else {
                int sub = col - 720;
                v += bkvp[sub];
                int axis = sub / 144, rem = sub % 144;
                kvpl[(size_t)row * 432 + rem * 3 + axis] = v;
            }
        }
    }
}

// ---------------------------------------------------------------------------
// K_PTS: local->global point transform + scatter
// ---------------------------------------------------------------------------
__global__ __launch_bounds__(192) void k_pts(
    const float* __restrict__ qpl, const float* __restrict__ kvpl,
    const float* __restrict__ t_rot, const float* __restrict__ t_trans,
    float* __restrict__ qpg,    // (B,N,144)
    float* __restrict__ kpT2,   // (B,12,512,12)
    float* __restrict__ vptsT)  // (B,12,24,512)
{
    const int row = blockIdx.x;
    const int b = row >> 9, n = row & 511;
    const int t = threadIdx.x;
    __shared__ float R[9], T[3];
    if (t < 9) R[t] = t_rot[(size_t)row * 9 + t];
    if (t < 3) T[t] = t_trans[(size_t)row * 3 + t];
    __syncthreads();
    float lx, ly, lz;
    if (t < 48) {
        lx = qpl[(size_t)row * 144 + t * 3 + 0];
        ly = qpl[(size_t)row * 144 + t * 3 + 1];
        lz = qpl[(size_t)row * 144 + t * 3 + 2];
    } else {
        int pp = t - 48;
        lx = kvpl[(size_t)row * 432 + pp * 3 + 0];
        ly = kvpl[(size_t)row * 432 + pp * 3 + 1];
        lz = kvpl[(size_t)row * 432 + pp * 3 + 2];
    }
    float gx = R[0] * lx + R[1] * ly + R[2] * lz + T[0];
    float gy = R[3] * lx + R[4] * ly + R[5] * lz + T[1];
    float gz = R[6] * lx + R[7] * ly + R[8] * lz + T[2];
    if (t < 48) {
        qpg[(size_t)row * 144 + t * 3 + 0] = gx;
        qpg[(size_t)row * 144 + t * 3 + 1] = gy;
        qpg[(size_t)row * 144 + t * 3 + 2] = gz;
    } else {
        int pp = t - 48;
        int h = pp / 12, pt = pp % 12;
        if (pt < 4) {
            size_t base = ((size_t)((b * 12 + h) << 9) + n) * 12 + pt * 3;
            kpT2[base + 0] = gx; kpT2[base + 1] = gy; kpT2[base + 2] = gz;
        } else {
            int base = (((b * 12 + h) * 24 + (pt - 4) * 3) << 9) + n;
            vptsT[base] = gx; vptsT[base + 512] = gy; vptsT[base + 1024] = gz;
        }
    }
}

// ---------------------------------------------------------------------------
// K_ATTN1P (round-17): round-13/16 internals, chunk HALVED to 64 j -> grid
// 8192. Rationale: 5 internal rewrites all landed 199-226 us; invariant is
// the per-block barrier chain (24 phases x 16 serial block-generations/CU).
// Halving the chunk halves the per-block critical path and doubles the
// number of independent chains the scheduler can overlap. LDS ~37.6 KB
// (l_s shrinks to 12x68) -> 4 blocks/CU.
// ---------------------------------------------------------------------------
__global__ __launch_bounds__(256) void k_attn1p(
    const float* __restrict__ q_o,   // (B,N,192)
    const float* __restrict__ kT2,   // (B,12,512,16)
    const float* __restrict__ qpg,   // (B,N,144)
    const float* __restrict__ kpT2,  // (B,12,512,12)
    const float* __restrict__ p,     // (B,N,N,128)
    const float* __restrict__ wb,    // (128,12)
    const float* __restrict__ bpb,   // (12)
    const float* __restrict__ hwts,  // (12)
    const float* __restrict__ mask,  // (B,N)
    float* __restrict__ e2,          // (8192, 768) unnormalized exp, block-major
    float* __restrict__ part)        // (8192, 1600)
{
    __shared__ __align__(16) float p_s[32 * 132];   // 16.9 KB tile; final 'red'
    __shared__ __align__(16) float l_s[12 * 68];    // base logits -> e in place
    __shared__ float red_s[3360];                   // [j32:105][q:13][h] pwb partials
    __shared__ __align__(16) float e_sT[32 * 20];   // e transposed for o_pair
    __shared__ __align__(16) float q_s[192];
    __shared__ __align__(16) float qp_s[144];
    __shared__ float hw_s[12];
    __shared__ float misc_s[2];

    const int bid = blockIdx.x;
    const int row = bid >> 3, jc = bid & 7;
    const int b = row >> 9, i = row & 511;
    const int j0 = jc * 64;
    const int t = threadIdx.x;
    const int cg = t & 31;          // c-quad (pwb + o_pair)
    const int jg = t >> 5;          // j-group for staging/pwb (0..7)
    const int hg = (t >> 5) & 1;    // h-half for o_pair
    const int wv = t >> 6;          // wave index
    const int lane = t & 63;

    const float* psrc = p + ((size_t)(b * 512 + i) * 512 + j0) * 128;
    const float4* p4 = (const float4*)psrc;  // 2048 f4 (64 j x 32 cq)

    for (int idx = t; idx < 192; idx += 256) q_s[idx] = q_o[(size_t)row * 192 + idx];
    for (int idx = t; idx < 144; idx += 256) qp_s[idx] = qpg[(size_t)row * 144 + idx];
    if (t < 12) {
        float x = hwts[t];
        float sp = (x > 20.f) ? x : log1pf(__expf(x));
        hw_s[t] = sp * HW_COEF;
    }
    if (t == 0) misc_s[0] = mask[row];

    // wb -> registers: this thread's 4 c x 12 h (one-time scattered loads)
    float wbr[4][12];
    #pragma unroll
    for (int cu = 0; cu < 4; ++cu)
        #pragma unroll
        for (int h = 0; h < 12; ++h)
            wbr[cu][h] = wb[(cg * 4 + cu) * 12 + h];

    // prefetch tile 0 (32 j): thread covers (j = jg + 8u, cq = cg)
    float4 rv[4];
    #pragma unroll
    for (int u = 0; u < 4; ++u) rv[u] = p4[t + 256 * u];

    __syncthreads();
    const float mi = misc_s[0];

    // phase 1: base logits for all 64 j (hides tile-0 load latency)
    {
        const float4* q4 = (const float4*)q_s;
        const float4* qp4 = (const float4*)qp_s;
        for (int idx = t; idx < 768; idx += 256) {
            int h = idx >> 6, jl = idx & 63;
            int j = j0 + jl;
            const float4* k4 = (const float4*)&kT2[((size_t)((b * 12 + h) << 9) + j) * 16];
            float qk = 0.f;
            #pragma unroll
            for (int c4 = 0; c4 < 4; ++c4) {
                float4 qv = q4[h * 4 + c4], kv = k4[c4];
                qk += qv.x * kv.x + qv.y * kv.y + qv.z * kv.z + qv.w * kv.w;
            }
            const float4* kp4 = (const float4*)&kpT2[((size_t)((b * 12 + h) << 9) + j) * 12];
            float d2 = 0.f;
            #pragma unroll
            for (int x = 0; x < 3; ++x) {
                float4 qp = qp4[h * 3 + x], kp = kp4[x];
                float dx = qp.x - kp.x, dy = qp.y - kp.y;
                float dz = qp.z - kp.z, dw = qp.w - kp.w;
                d2 += dx * dx + dy * dy + dz * dz + dw * dw;
            }
            float mj = mask[b * 512 + j];
            l_s[h * 68 + jl] = QK_SCALE * qk - 0.5f * hw_s[h] * d2
                               + BB_SCALE * bpb[h] + 100000.0f * (mi * mj - 1.0f);
        }
    }

    float acc[6][4] = {};
    const int hsub = cg & 3, qq = cg >> 2;

    for (int tile = 0; tile < 2; ++tile) {
        __syncthreads();                     // p_s, red_s, e_sT reusable
        // stage tile to LDS + pwb partials from the SAME registers
        #pragma unroll
        for (int u = 0; u < 4; ++u) {
            int j32 = jg + 8 * u;
            *(float4*)&p_s[j32 * 132 + cg * 4] = rv[u];
            float partial[12];
            #pragma unroll
            for (int h = 0; h < 12; ++h)
                partial[h] = rv[u].x * wbr[0][h] + rv[u].y * wbr[1][h]
                           + rv[u].z * wbr[2][h] + rv[u].w * wbr[3][h];
            #pragma unroll
            for (int h = 0; h < 12; ++h) {
                partial[h] += __shfl_xor(partial[h], 1, 64);   // quad DPP
                partial[h] += __shfl_xor(partial[h], 2, 64);   // quad DPP
            }
            // all lanes hold the quad sum; lane writes its 3-h slice (j-major)
            #pragma unroll
            for (int k = 0; k < 3; ++k)
                red_s[j32 * 105 + qq * 13 + hsub * 3 + k] = partial[hsub * 3 + k];
        }
        __syncthreads();                     // p_s + red_s ready
        if (tile < 1) {
            #pragma unroll
            for (int u = 0; u < 4; ++u)
                rv[u] = p4[1024 + t + 256 * u];
        }
        // e-phase: gather 8 q-partials per (j,h); e -> l_s + e_sT
        for (int idx = t; idx < 384; idx += 256) {
            int h = idx >> 5, j32 = idx & 31;
            float pwb = 0.f;
            #pragma unroll
            for (int q = 0; q < 8; ++q) pwb += red_s[j32 * 105 + q * 13 + h];
            int jl = tile * 32 + j32;
            float e = __expf(l_s[h * 68 + jl] + BB_SCALE * pwb);
            l_s[h * 68 + jl] = e;
            e_sT[j32 * 20 + h + 2 * (h >= 6)] = e;
        }
        __syncthreads();                     // e visible
        // o_pair accumulate: acc[h][c] += e[h][j] * p[j][c]; e as b128+b64
        #pragma unroll
        for (int uu = 0; uu < 8; ++uu) {
            int jt = wv * 8 + uu;
            float4 pb = *(const float4*)&p_s[jt * 132 + cg * 4];
            float4 ea = *(const float4*)&e_sT[jt * 20 + hg * 8];
            float2 eb = *(const float2*)&e_sT[jt * 20 + hg * 8 + 4];
            float ev[6] = {ea.x, ea.y, ea.z, ea.w, eb.x, eb.y};
            #pragma unroll
            for (int hh = 0; hh < 6; ++hh) {
                acc[hh][0] += ev[hh] * pb.x; acc[hh][1] += ev[hh] * pb.y;
                acc[hh][2] += ev[hh] * pb.z; acc[hh][3] += ev[hh] * pb.w;
            }
        }
    }

    const size_t po = (size_t)bid * PART_STRIDE;
    __syncthreads();
    // bulk e2 write: one contiguous 3 KB chunk per block
    for (int idx = t; idx < 768; idx += 256)
        e2[(size_t)bid * 768 + idx] = l_s[(idx >> 6) * 68 + (idx & 63)];
    // s sums from l_s: per-wave 3 h (64 j = one lane each)
    #pragma unroll
    for (int k = 0; k < 3; ++k) {
        int h = wv * 3 + k;
        float sv = l_s[h * 68 + lane];
        #pragma unroll
        for (int o = 32; o > 0; o >>= 1) sv += __shfl_xor(sv, o, 64);
        if (lane == 0) part[po + h] = sv;
    }

    // o_pair partial reduce over 4 wv, per h-half round; red overlays p_s
    __syncthreads();
    float* red = p_s;   // [4 wv][32 cg] stride 25 -> conflict-free
    #pragma unroll
    for (int round = 0; round < 2; ++round) {
        if (hg == round) {
            #pragma unroll
            for (int hh = 0; hh < 6; ++hh)
                #pragma unroll
                for (int u = 0; u < 4; ++u)
                    red[(wv * 32 + cg) * 25 + hh * 4 + u] = acc[hh][u];
        }
        __syncthreads();
        for (int idx = t; idx < 768; idx += 256) {
            int hh = idx >> 7, c = idx & 127;
            int cgg = c >> 2, uu = c & 3;
            float sv = red[(0 * 32 + cgg) * 25 + hh * 4 + uu]
                     + red[(1 * 32 + cgg) * 25 + hh * 4 + uu]
                     + red[(2 * 32 + cgg) * 25 + hh * 4 + uu]
                     + red[(3 * 32 + cgg) * 25 + hh * 4 + uu];
            part[po + 12 + (round * 6 + hh) * 128 + c] = sv;
        }
        __syncthreads();
    }
}

// ---------------------------------------------------------------------------
// K_FINISH: merges 8 chunk-partials; e held in REGISTERS per wave-head
// (round-15 win). e2 layout: per-64-j-chunk block-major [chunk][h*64+jl].
// ---------------------------------------------------------------------------
__global__ __launch_bounds__(256) void k_finish(
    const float* __restrict__ part, const float* __restrict__ e2,
    const float* __restrict__ vT, const float* __restrict__ vptsT,
    const float* __restrict__ t_rot, const float* __restrict__ t_trans,
    float* __restrict__ feats)
{
    __shared__ float inv_s[12];
    __shared__ __align__(16) float optg_s[288];
    __shared__ float R_s[9], T_s[3];
    __shared__ float red[480 * 17];
    const int row = blockIdx.x;
    const int b = row >> 9;
    const int t = threadIdx.x;
    const size_t pb = (size_t)row * 8 * PART_STRIDE;
    const size_t eb = (size_t)row * 8 * 768;
    if (t < 12) {
        float sv = 0.f;
        #pragma unroll
        for (int q = 0; q < 8; ++q) sv += part[pb + (size_t)q * PART_STRIDE + t];
        inv_s[t] = 1.0f / sv;
    }
    if (t < 9) R_s[t] = t_rot[(size_t)row * 9 + t];
    if (t < 3) T_s[t] = t_trans[(size_t)row * 3 + t];
    __syncthreads();

    size_t fb = (size_t)row * 2112;
    for (int idx = t; idx < 1536; idx += 256) {
        int h = idx >> 7;
        float sv = 0.f;
        #pragma unroll
        for (int q = 0; q < 8; ++q)
            sv += part[pb + (size_t)q * PART_STRIDE + 12 + idx];
        feats[fb + 576 + idx] = sv * inv_s[h];
    }

    const int wv = t >> 6, lane = t & 63;
    // e-rows for this wave's 3 heads -> registers
    float4 er[3][2];
    #pragma unroll
    for (int k = 0; k < 3; ++k) {
        int h = wv * 3 + k;
        int jq0 = lane, jq1 = lane + 64;   // float4 index in [0,128)
        er[k][0] = *(const float4*)&e2[eb + (size_t)(jq0 >> 4) * 768 + h * 64 + (jq0 & 15) * 4];
        er[k][1] = *(const float4*)&e2[eb + (size_t)(jq1 >> 4) * 768 + h * 64 + (jq1 & 15) * 4];
    }
    #pragma unroll
    for (int k = 0; k < 3; ++k) {
        int h = wv * 3 + k;
        const float* vbase  = vT + ((size_t)((b * 12 + h) * 16) << 9);
        const float* vpbase = vptsT + ((size_t)((b * 12 + h) * 24) << 9);
        for (int ol = 0; ol < 40; ++ol) {
            const float* src; int oi;
            if (ol < 16) { oi = h * 16 + ol;            src = vbase + (ol << 9); }
            else         { int pt = ol - 16; oi = 192 + h * 24 + pt; src = vpbase + (pt << 9); }
            const float4* s4 = (const float4*)src;
            float4 v0 = s4[lane], v1 = s4[lane + 64];
            float accv = er[k][0].x * v0.x + er[k][0].y * v0.y
                       + er[k][0].z * v0.z + er[k][0].w * v0.w
                       + er[k][1].x * v1.x + er[k][1].y * v1.y
                       + er[k][1].z * v1.z + er[k][1].w * v1.w;
            accv += __shfl_xor(accv, 1, 64);   // quad DPP
            accv += __shfl_xor(accv, 2, 64);   // quad DPP
            if ((lane & 3) == 0) red[oi * 17 + (lane >> 2)] = accv;
        }
    }
    __syncthreads();
    for (int idx = t; idx < 480; idx += 256) {
        int h = (idx < 192) ? (idx >> 4) : ((idx - 192) / 24);
        float sv = 0.f;
        #pragma unroll
        for (int q = 0; q < 16; ++q) sv += red[idx * 17 + q];
        sv *= inv_s[h];
        if (idx < 192) feats[fb + idx] = sv;
        else           optg_s[idx - 192] = sv;
    }
    __syncthreads();

    if (t < 96) {
        float gx = optg_s[t * 3 + 0] - T_s[0];
        float gy = optg_s[t * 3 + 1] - T_s[1];
        float gz = optg_s[t * 3 + 2] - T_s[2];
        float ox = R_s[0] * gx + R_s[3] * gy + R_s[6] * gz;
        float oy = R_s[1] * gx + R_s[4] * gy + R_s[7] * gz;
        float oz = R_s[2] * gx + R_s[5] * gy + R_s[8] * gz;
        float nrm = sqrtf(ox * ox + oy * oy + oz * oz + 1e-8f);
        feats[fb + 192 + t] = ox;
        feats[fb + 288 + t] = oy;
        feats[fb + 384 + t] = oz;
        feats[fb + 480 + t] = nrm;
    }
}

// ---------------------------------------------------------------------------
// K_GEMM: tiled f32 GEMM, 32r x 128c per block, 4x4/thread, split-K via z.
// A-source = sum of n_parts partials (stride 393216) [+abias] [relu].
// ---------------------------------------------------------------------------
__global__ __launch_bounds__(256) void k_gemm(
    const float* __restrict__ A0, int n_parts,
    const float* __restrict__ abias, int lda,
    const float* __restrict__ W,
    float* __restrict__ out, int k_chunks, int do_relu)
{
    __shared__ __align__(16) float A_t[64 * 36];
    __shared__ __align__(16) float W_s[64 * 132];
    const int row0 = blockIdx.x * 32;
    const int C0 = blockIdx.y * 128;
    const int k_base = blockIdx.z * k_chunks * 64;
    const int t = threadIdx.x;
    const int cq = t & 31, rq = t >> 5;
    float acc[4][4] = {};
    for (int ch = 0; ch < k_chunks; ++ch) {
        const int k0 = k_base + ch * 64;
        __syncthreads();
        for (int idx = t; idx < 512; idx += 256) {
            int r = idx & 31, kq = idx >> 5;
            float4 a = *(const float4*)&A0[(size_t)(row0 + r) * lda + k0 + kq * 4];
            for (int q = 1; q < n_parts; ++q) {
                float4 a1 = *(const float4*)&A0[(size_t)q * 393216 +
                                                (size_t)(row0 + r) * lda + k0 + kq * 4];
                a.x += a1.x; a.y += a1.y; a.z += a1.z; a.w += a1.w;
            }
            if (abias) {
                float4 ab = *(const float4*)&abias[k0 + kq * 4];
                a.x += ab.x; a.y += ab.y; a.z += ab.z; a.w += ab.w;
            }
            if (do_relu) {
                a.x = fmaxf(a.x, 0.f); a.y = fmaxf(a.y, 0.f);
                a.z = fmaxf(a.z, 0.f); a.w = fmaxf(a.w, 0.f);
            }
            A_t[(kq * 4 + 0) * 36 + r] = a.x;
            A_t[(kq * 4 + 1) * 36 + r] = a.y;
            A_t[(kq * 4 + 2) * 36 + r] = a.z;
            A_t[(kq * 4 + 3) * 36 + r] = a.w;
        }
        for (int idx = t; idx < 2048; idx += 256) {
            int kk = idx >> 5, c4 = idx & 31;
            *(float4*)&W_s[kk * 132 + c4 * 4] =
                *(const float4*)&W[(size_t)(k0 + kk) * 384 + C0 + c4 * 4];
        }
        __syncthreads();
        #pragma unroll 8
        for (int kk = 0; kk < 64; ++kk) {
            float4 a4 = *(const float4*)&A_t[kk * 36 + rq * 4];
            float4 w4 = *(const float4*)&W_s[kk * 132 + cq * 4];
            acc[0][0] += a4.x * w4.x; acc[0][1] += a4.x * w4.y; acc[0][2] += a4.x * w4.z; acc[0][3] += a4.x * w4.w;
            acc[1][0] += a4.y * w4.x; acc[1][1] += a4.y * w4.y; acc[1][2] += a4.y * w4.z; acc[1][3] += a4.y * w4.w;
            acc[2][0] += a4.z * w4.x; acc[2][1] += a4.z * w4.y; acc[2][2] += a4.z * w4.z; acc[2][3] += a4.z * w4.w;
            acc[3][0] += a4.w * w4.x; acc[3][1] += a4.w * w4.y; acc[3][2] += a4.w * w4.z; acc[3][3] += a4.w * w4.w;
        }
    }
    float* outp = out + (size_t)blockIdx.z * 393216;
    #pragma unroll
    for (int r = 0; r < 4; ++r) {
        float4 st = { acc[r][0], acc[r][1], acc[r][2], acc[r][3] };
        *(float4*)&outp[(size_t)(row0 + rq * 4 + r) * 384 + C0 + cq * 4] = st;
    }
}

// ---------------------------------------------------------------------------
// K_LNSUM: out = LN( sum(parts) + bias + resid ), one wave per row.
// If w_bb != null, also computes the fused backbone update.
// ---------------------------------------------------------------------------
__global__ __launch_bounds__(256) void k_lnsum(
    const float* __restrict__ parts, int np,
    const float* __restrict__ bias, const float* __restrict__ resid,
    const float* __restrict__ g, const float* __restrict__ bta,
    float* __restrict__ o,
    const float* __restrict__ w_bb, const float* __restrict__ b_bb,
    const float* __restrict__ t_rot, const float* __restrict__ t_trans,
    float* __restrict__ rot_out, float* __restrict__ trans_out)
{
    const int wid = (blockIdx.x * 256 + threadIdx.x) >> 6;
    const int lane = threadIdx.x & 63;
    float v[6], sum = 0.f, sq = 0.f;
    #pragma unroll
    for (int u = 0; u < 6; ++u) {
        int c = lane + 64 * u;
        float x = bias[c] + resid[(size_t)wid * 384 + c];
        for (int q = 0; q < np; ++q)
            x += parts[(size_t)q * 393216 + (size_t)wid * 384 + c];
        v[u] = x; sum += x; sq += x * x;
    }
    #pragma unroll
    for (int off = 32; off > 0; off >>= 1) {
        sum += __shfl_xor(sum, off, 64);
        sq  += __shfl_xor(sq, off, 64);
    }
    float mean = sum * (1.f / 384.f);
    float var = sq * (1.f / 384.f) - mean * mean;
    float rst = rsqrtf(var + 1e-5f);
    #pragma unroll
    for (int u = 0; u < 6; ++u) {
        int c = lane + 64 * u;
        v[u] = (v[u] - mean) * rst * g[c] + bta[c];
        o[(size_t)wid * 384 + c] = v[u];
    }
    if (!w_bb) return;

    float uacc[6] = {0.f, 0.f, 0.f, 0.f, 0.f, 0.f};
    #pragma unroll
    for (int u = 0; u < 6; ++u) {
        int c = lane + 64 * u;
        #pragma unroll
        for (int j = 0; j < 6; ++j) uacc[j] += v[u] * w_bb[c * 6 + j];
    }
    #pragma unroll
    for (int j = 0; j < 6; ++j) {
        #pragma unroll
        for (int off = 32; off > 0; off >>= 1) uacc[j] += __shfl_xor(uacc[j], off, 64);
    }
    if (lane == 0) {
        #pragma unroll
        for (int j = 0; j < 6; ++j) uacc[j] += b_bb[j];
        float bq = uacc[0], cq = uacc[1], dq = uacc[2];
        float inv = rsqrtf(1.f + bq * bq + cq * cq + dq * dq);
        float a = inv, bqn = bq * inv, cqn = cq * inv, dqn = dq * inv;
        float R[9];
        R[0] = a * a + bqn * bqn - cqn * cqn - dqn * dqn;
        R[1] = 2.f * (bqn * cqn - a * dqn);
        R[2] = 2.f * (bqn * dqn + a * cqn);
        R[3] = 2.f * (bqn * cqn + a * dqn);
        R[4] = a * a - bqn * bqn + cqn * cqn - dqn * dqn;
        R[5] = 2.f * (cqn * dqn - a * bqn);
        R[6] = 2.f * (bqn * dqn - a * cqn);
        R[7] = 2.f * (cqn * dqn + a * bqn);
        R[8] = a * a - bqn * bqn - cqn * cqn + dqn * dqn;
        const float* Rt = t_rot + (size_t)wid * 9;
        #pragma unroll
        for (int i2 = 0; i2 < 3; ++i2) {
            #pragma unroll
            for (int k2 = 0; k2 < 3; ++k2) {
                rot_out[(size_t)wid * 9 + i2 * 3 + k2] =
                    Rt[i2 * 3 + 0] * R[0 + k2] + Rt[i2 * 3 + 1] * R[3 + k2] + Rt[i2 * 3 + 2] * R[6 + k2];
            }
            trans_out[(size_t)wid * 3 + i2] =
                Rt[i2 * 3 + 0] * uacc[3] + Rt[i2 * 3 + 1] * uacc[4] + Rt[i2 * 3 + 2] * uacc[5]
                + t_trans[(size_t)wid * 3 + i2];
        }
    }
}

// ---------------------------------------------------------------------------
extern "C" void kernel_launch(void* const* d_in, const int* in_sizes, int n_in,
                              void* d_out, int out_size, void* d_ws, size_t ws_size,
                              hipStream_t stream) {
    const float* s      = (const float*)d_in[0];
    const float* p      = (const float*)d_in[1];
    const float* t_rot  = (const float*)d_in[2];
    const float* t_trans= (const float*)d_in[3];
    const float* mask   = (const float*)d_in[4];
    const float* wq     = (const float*)d_in[5];
    const float* bq     = (const float*)d_in[6];
    const float* wkv    = (const float*)d_in[7];
    const float* bkv    = (const float*)d_in[8];
    const float* wqp    = (const float*)d_in[9];
    const float* bqp    = (const float*)d_in[10];
    const float* wkvp   = (const float*)d_in[11];
    const float* bkvp   = (const float*)d_in[12];
    const float* wb     = (const float*)d_in[13];
    const float* bpb    = (const float*)d_in[14];
    const float* hwts   = (const float*)d_in[15];
    const float* w_out  = (const float*)d_in[16];
    const float* b_out  = (const float*)d_in[17];
    const float* ln1s   = (const float*)d_in[18];
    const float* ln1b   = (const float*)d_in[19];
    const float* wt1    = (const float*)d_in[20];
    const float* bt1    = (const float*)d_in[21];
    const float* wt2    = (const float*)d_in[22];
    const float* bt2    = (const float*)d_in[23];
    const float* wt3    = (const float*)d_in[24];
    const float* bt3    = (const float*)d_in[25];
    const float* ln2s   = (const float*)d_in[26];
    const float* ln2b   = (const float*)d_in[27];
    const float* w_bb   = (const float*)d_in[28];
    const float* b_bb   = (const float*)d_in[29];
    float* out = (float*)d_out;
    float* ws  = (float*)d_ws;

    float* q_o   = ws;                    // 196608
    float* kT2   = q_o   + 196608;        // 196608
    float* vT    = kT2   + 196608;        // 196608
    float* qpl   = vT    + 196608;        // 147456
    float* qpg   = qpl   + 147456;        // 147456
    float* kvpl  = qpg   + 147456;        // 442368
    float* kpT2  = kvpl  + 442368;        // 147456
    float* vptsT = kpT2  + 147456;        // 294912
    float* feats = vptsT + 294912;        // 2162688
    float* s1    = feats + 2162688;       // 393216
    float* e2    = s1    + 393216;        // 6291456: e2 (attn) -> gparts (out-proj)
    float* partb = e2    + 6291456;       // 13107200: attn parts -> t1/t2/t3 partials
    float* partb2= partb + 2359296;       // second 6-partial region (within partb)

    k_proj<<<dim3(32, 9), 256, 0, stream>>>(s, wq, bq, wkv, bkv, wqp, bqp, wkvp, bkvp,
                                            q_o, kT2, vT, qpl, kvpl);
    k_pts<<<1024, 192, 0, stream>>>(qpl, kvpl, t_rot, t_trans, qpg, kpT2, vptsT);
    k_attn1p<<<8192, 256, 0, stream>>>(q_o, kT2, qpg, kpT2, p, wb, bpb, hwts,
                                       mask, e2, partb);
    k_finish<<<1024, 256, 0, stream>>>(partb, e2, vT, vptsT, t_rot, t_trans, feats);
    // out-proj: split-K 11 x 192 (grid 1056). partials reuse e2 (dead).
    k_gemm<<<dim3(32, 3, 11), 256, 0, stream>>>(feats, 1, nullptr, 2112,
                                                w_out, e2, 3, 0);
    k_lnsum<<<256, 256, 0, stream>>>(e2, 11, b_out, s, ln1s, ln1b, s1,
                                     nullptr, nullptr, nullptr, nullptr,
                                     nullptr, nullptr);
    // transitions: split-K 6 x 64 each (grid 576); partial-sum+bias+relu fused
    // into the consumer's A-load (n_parts).
    k_gemm<<<dim3(32, 3, 6), 256, 0, stream>>>(s1, 1, nullptr, 384,
                                               wt1, partb, 1, 0);
    k_gemm<<<dim3(32, 3, 6), 256, 0, stream>>>(partb, 6, bt1, 384,
                                               wt2, partb2, 1, 1);
    k_gemm<<<dim3(32, 3, 6), 256, 0, stream>>>(partb2, 6, bt2, 384,
                                               wt3, partb, 1, 1);
    k_lnsum<<<256, 256, 0, stream>>>(partb, 6, bt3, s1, ln2s, ln2b, out,
                                     w_bb, b_bb, t_rot, t_trans,
                                     out + 393216, out + 402432);
}

// Round 18
// 368.568 us; speedup vs baseline: 1.2565x; 1.2565x over previous
//
#include <hip/hip_runtime.h>
#include <math.h>

#define QK_SCALE 0.14433756729740643f   // 1/sqrt(3*16)
#define BB_SCALE 0.57735026918962576f   // 1/sqrt(3)
#define HW_COEF  0.13608276348795434f   // 1/sqrt(54)

// part layout per (row,jc2), stride 1600 floats:
// [0:12] s_sum, [12:1548] o_pair partial (h*128+c)
#define PART_STRIDE 1600

// ---------------------------------------------------------------------------
// K_PROJ: tiled GEMM (1024x384)@(384x1152 composite) with scatter epilogue.
// ---------------------------------------------------------------------------
__global__ __launch_bounds__(256) void k_proj(
    const float* __restrict__ s,
    const float* __restrict__ wq,  const float* __restrict__ bq,
    const float* __restrict__ wkv, const float* __restrict__ bkv,
    const float* __restrict__ wqp, const float* __restrict__ bqp,
    const float* __restrict__ wkvp,const float* __restrict__ bkvp,
    float* __restrict__ q_o,    // (B,N,192)
    float* __restrict__ kT2,    // (B,12,512,16)
    float* __restrict__ vT,     // (B,12,16,512)
    float* __restrict__ qpl,    // (B,N,48,3) local
    float* __restrict__ kvpl)   // (B,N,144,3) local
{
    __shared__ __align__(16) float A_t[64 * 36];
    __shared__ __align__(16) float W_s[64 * 132];
    const int row0 = blockIdx.x * 32;
    const int C0 = blockIdx.y * 128;
    const int t = threadIdx.x;
    const int cq = t & 31, rq = t >> 5;
    float acc[4][4] = {};
    for (int ch = 0; ch < 6; ++ch) {
        const int k0 = ch * 64;
        __syncthreads();
        for (int idx = t; idx < 512; idx += 256) {
            int r = idx & 31, kq = idx >> 5;
            float4 a = *(const float4*)&s[(size_t)(row0 + r) * 384 + k0 + kq * 4];
            A_t[(kq * 4 + 0) * 36 + r] = a.x;
            A_t[(kq * 4 + 1) * 36 + r] = a.y;
            A_t[(kq * 4 + 2) * 36 + r] = a.z;
            A_t[(kq * 4 + 3) * 36 + r] = a.w;
        }
        for (int idx = t; idx < 2048; idx += 256) {
            int kk = idx >> 5, c4 = idx & 31;
            int C4 = C0 + c4 * 4;
            const float* w; int sub, wcols;
            if (C4 < 192)      { w = wq;   sub = C4;       wcols = 192; }
            else if (C4 < 576) { w = wkv;  sub = C4 - 192; wcols = 384; }
            else if (C4 < 720) { w = wqp;  sub = C4 - 576; wcols = 144; }
            else               { w = wkvp; sub = C4 - 720; wcols = 432; }
            *(float4*)&W_s[kk * 132 + c4 * 4] =
                *(const float4*)&w[(size_t)(k0 + kk) * wcols + sub];
        }
        __syncthreads();
        #pragma unroll 8
        for (int kk = 0; kk < 64; ++kk) {
            float4 a4 = *(const float4*)&A_t[kk * 36 + rq * 4];
            float4 w4 = *(const float4*)&W_s[kk * 132 + cq * 4];
            acc[0][0] += a4.x * w4.x; acc[0][1] += a4.x * w4.y; acc[0][2] += a4.x * w4.z; acc[0][3] += a4.x * w4.w;
            acc[1][0] += a4.y * w4.x; acc[1][1] += a4.y * w4.y; acc[1][2] += a4.y * w4.z; acc[1][3] += a4.y * w4.w;
            acc[2][0] += a4.z * w4.x; acc[2][1] += a4.z * w4.y; acc[2][2] += a4.z * w4.z; acc[2][3] += a4.z * w4.w;
            acc[3][0] += a4.w * w4.x; acc[3][1] += a4.w * w4.y; acc[3][2] += a4.w * w4.z; acc[3][3] += a4.w * w4.w;
        }
    }
    #pragma unroll
    for (int r = 0; r < 4; ++r) {
        int row = row0 + rq * 4 + r;
        int b = row >> 9, n = row & 511;
        #pragma unroll
        for (int u = 0; u < 4; ++u) {
            int col = C0 + cq * 4 + u;
            float v = acc[r][u];
            if (col < 192) {
                q_o[(size_t)row * 192 + col] = v + bq[col];
            } else if (col < 576) {
                int sub = col - 192;
                v += bkv[sub];
                int h = sub >> 5, rr = sub & 31;
                if (rr < 16) kT2[((size_t)((b * 12 + h) << 9) + n) * 16 + rr] = v;
                else         vT[(((b * 12 + h) * 16 + (rr - 16)) << 9) + n] = v;
            } else if (col < 720) {
                int sub = col - 576;
                v += bqp[sub];
                int axis = sub / 48, rem = sub % 48;
                qpl[(size_t)row * 144 + rem * 3 + axis] = v;
            } else {
                int sub = col - 720;
                v += bkvp[sub];
                int axis = sub / 144, rem = sub % 144;
                kvpl[(size_t)row * 432 + rem * 3 + axis] = v;
            }
        }
    }
}

// ---------------------------------------------------------------------------
// K_PTS: local->global point transform + scatter
// ---------------------------------------------------------------------------
__global__ __launch_bounds__(192) void k_pts(
    const float* __restrict__ qpl, const float* __restrict__ kvpl,
    const float* __restrict__ t_rot, const float* __restrict__ t_trans,
    float* __restrict__ qpg,    // (B,N,144)
    float* __restrict__ kpT2,   // (B,12,512,12)
    float* __restrict__ vptsT)  // (B,12,24,512)
{
    const int row = blockIdx.x;
    const int b = row >> 9, n = row & 511;
    const int t = threadIdx.x;
    __shared__ float R[9], T[3];
    if (t < 9) R[t] = t_rot[(size_t)row * 9 + t];
    if (t < 3) T[t] = t_trans[(size_t)row * 3 + t];
    __syncthreads();
    float lx, ly, lz;
    if (t < 48) {
        lx = qpl[(size_t)row * 144 + t * 3 + 0];
        ly = qpl[(size_t)row * 144 + t * 3 + 1];
        lz = qpl[(size_t)row * 144 + t * 3 + 2];
    } else {
        int pp = t - 48;
        lx = kvpl[(size_t)row * 432 + pp * 3 + 0];
        ly = kvpl[(size_t)row * 432 + pp * 3 + 1];
        lz = kvpl[(size_t)row * 432 + pp * 3 + 2];
    }
    float gx = R[0] * lx + R[1] * ly + R[2] * lz + T[0];
    float gy = R[3] * lx + R[4] * ly + R[5] * lz + T[1];
    float gz = R[6] * lx + R[7] * ly + R[8] * lz + T[2];
    if (t < 48) {
        qpg[(size_t)row * 144 + t * 3 + 0] = gx;
        qpg[(size_t)row * 144 + t * 3 + 1] = gy;
        qpg[(size_t)row * 144 + t * 3 + 2] = gz;
    } else {
        int pp = t - 48;
        int h = pp / 12, pt = pp % 12;
        if (pt < 4) {
            size_t base = ((size_t)((b * 12 + h) << 9) + n) * 12 + pt * 3;
            kpT2[base + 0] = gx; kpT2[base + 1] = gy; kpT2[base + 2] = gz;
        } else {
            int base = (((b * 12 + h) * 24 + (pt - 4) * 3) << 9) + n;
            vptsT[base] = gx; vptsT[base + 512] = gy; vptsT[base + 1024] = gz;
        }
    }
}

// ---------------------------------------------------------------------------
// K_ATTN1P (round-18): round-13/16 internals, chunk DOUBLED to 256 j ->
// grid 2048. Chunk-size scan: 64j/640 phases/CU = 238 us; 128j/512 = 200 us;
// time tracks total barrier-phases per CU, so 256j (~240 phases/CU, 8
// generations of 8-tile blocks) extrapolates to ~185 us. LDS ~45.7 KB
// (l_s 12x260) -> 3 blocks/CU, same residency as the best 128j variant.
// ---------------------------------------------------------------------------
__global__ __launch_bounds__(256) void k_attn1p(
    const float* __restrict__ q_o,   // (B,N,192)
    const float* __restrict__ kT2,   // (B,12,512,16)
    const float* __restrict__ qpg,   // (B,N,144)
    const float* __restrict__ kpT2,  // (B,12,512,12)
    const float* __restrict__ p,     // (B,N,N,128)
    const float* __restrict__ wb,    // (128,12)
    const float* __restrict__ bpb,   // (12)
    const float* __restrict__ hwts,  // (12)
    const float* __restrict__ mask,  // (B,N)
    float* __restrict__ e2,          // (2048, 3072) unnormalized exp, block-major
    float* __restrict__ part)        // (2048, 1600)
{
    __shared__ __align__(16) float p_s[32 * 132];   // 16.9 KB tile; final 'red'
    __shared__ __align__(16) float l_s[12 * 260];   // base logits -> e in place
    __shared__ float red_s[3360];                   // [j32:105][q:13][h] pwb partials
    __shared__ __align__(16) float e_sT[32 * 20];   // e transposed for o_pair
    __shared__ __align__(16) float q_s[192];
    __shared__ __align__(16) float qp_s[144];
    __shared__ float hw_s[12];
    __shared__ float misc_s[2];

    const int bid = blockIdx.x;
    const int row = bid >> 1, jc = bid & 1;
    const int b = row >> 9, i = row & 511;
    const int j0 = jc * 256;
    const int t = threadIdx.x;
    const int cg = t & 31;          // c-quad (pwb + o_pair)
    const int jg = t >> 5;          // j-group for staging/pwb (0..7)
    const int hg = (t >> 5) & 1;    // h-half for o_pair
    const int wv = t >> 6;          // wave index
    const int lane = t & 63;

    const float* psrc = p + ((size_t)(b * 512 + i) * 512 + j0) * 128;
    const float4* p4 = (const float4*)psrc;  // 8192 f4 (256 j x 32 cq)

    for (int idx = t; idx < 192; idx += 256) q_s[idx] = q_o[(size_t)row * 192 + idx];
    for (int idx = t; idx < 144; idx += 256) qp_s[idx] = qpg[(size_t)row * 144 + idx];
    if (t < 12) {
        float x = hwts[t];
        float sp = (x > 20.f) ? x : log1pf(__expf(x));
        hw_s[t] = sp * HW_COEF;
    }
    if (t == 0) misc_s[0] = mask[row];

    // wb -> registers: this thread's 4 c x 12 h (one-time scattered loads)
    float wbr[4][12];
    #pragma unroll
    for (int cu = 0; cu < 4; ++cu)
        #pragma unroll
        for (int h = 0; h < 12; ++h)
            wbr[cu][h] = wb[(cg * 4 + cu) * 12 + h];

    // prefetch tile 0 (32 j): thread covers (j = jg + 8u, cq = cg)
    float4 rv[4];
    #pragma unroll
    for (int u = 0; u < 4; ++u) rv[u] = p4[t + 256 * u];

    __syncthreads();
    const float mi = misc_s[0];

    // phase 1: base logits for all 256 j (hides tile-0 load latency)
    {
        const float4* q4 = (const float4*)q_s;
        const float4* qp4 = (const float4*)qp_s;
        for (int idx = t; idx < 3072; idx += 256) {
            int h = idx >> 8, jl = idx & 255;
            int j = j0 + jl;
            const float4* k4 = (const float4*)&kT2[((size_t)((b * 12 + h) << 9) + j) * 16];
            float qk = 0.f;
            #pragma unroll
            for (int c4 = 0; c4 < 4; ++c4) {
                float4 qv = q4[h * 4 + c4], kv = k4[c4];
                qk += qv.x * kv.x + qv.y * kv.y + qv.z * kv.z + qv.w * kv.w;
            }
            const float4* kp4 = (const float4*)&kpT2[((size_t)((b * 12 + h) << 9) + j) * 12];
            float d2 = 0.f;
            #pragma unroll
            for (int x = 0; x < 3; ++x) {
                float4 qp = qp4[h * 3 + x], kp = kp4[x];
                float dx = qp.x - kp.x, dy = qp.y - kp.y;
                float dz = qp.z - kp.z, dw = qp.w - kp.w;
                d2 += dx * dx + dy * dy + dz * dz + dw * dw;
            }
            float mj = mask[b * 512 + j];
            l_s[h * 260 + jl] = QK_SCALE * qk - 0.5f * hw_s[h] * d2
                                + BB_SCALE * bpb[h] + 100000.0f * (mi * mj - 1.0f);
        }
    }

    float acc[6][4] = {};
    const int hsub = cg & 3, qq = cg >> 2;

    for (int tile = 0; tile < 8; ++tile) {
        __syncthreads();                     // p_s, red_s, e_sT reusable
        // stage tile to LDS + pwb partials from the SAME registers
        #pragma unroll
        for (int u = 0; u < 4; ++u) {
            int j32 = jg + 8 * u;
            *(float4*)&p_s[j32 * 132 + cg * 4] = rv[u];
            float partial[12];
            #pragma unroll
            for (int h = 0; h < 12; ++h)
                partial[h] = rv[u].x * wbr[0][h] + rv[u].y * wbr[1][h]
                           + rv[u].z * wbr[2][h] + rv[u].w * wbr[3][h];
            #pragma unroll
            for (int h = 0; h < 12; ++h) {
                partial[h] += __shfl_xor(partial[h], 1, 64);   // quad DPP
                partial[h] += __shfl_xor(partial[h], 2, 64);   // quad DPP
            }
            // all lanes hold the quad sum; lane writes its 3-h slice (j-major)
            #pragma unroll
            for (int k = 0; k < 3; ++k)
                red_s[j32 * 105 + qq * 13 + hsub * 3 + k] = partial[hsub * 3 + k];
        }
        __syncthreads();                     // p_s + red_s ready
        if (tile < 7) {
            #pragma unroll
            for (int u = 0; u < 4; ++u)
                rv[u] = p4[(tile + 1) * 1024 + t + 256 * u];
        }
        // e-phase: gather 8 q-partials per (j,h); e -> l_s + e_sT
        for (int idx = t; idx < 384; idx += 256) {
            int h = idx >> 5, j32 = idx & 31;
            float pwb = 0.f;
            #pragma unroll
            for (int q = 0; q < 8; ++q) pwb += red_s[j32 * 105 + q * 13 + h];
            int jl = tile * 32 + j32;
            float e = __expf(l_s[h * 260 + jl] + BB_SCALE * pwb);
            l_s[h * 260 + jl] = e;
            e_sT[j32 * 20 + h + 2 * (h >= 6)] = e;
        }
        __syncthreads();                     // e visible
        // o_pair accumulate: acc[h][c] += e[h][j] * p[j][c]; e as b128+b64
        #pragma unroll
        for (int uu = 0; uu < 8; ++uu) {
            int jt = wv * 8 + uu;
            float4 pb = *(const float4*)&p_s[jt * 132 + cg * 4];
            float4 ea = *(const float4*)&e_sT[jt * 20 + hg * 8];
            float2 eb = *(const float2*)&e_sT[jt * 20 + hg * 8 + 4];
            float ev[6] = {ea.x, ea.y, ea.z, ea.w, eb.x, eb.y};
            #pragma unroll
            for (int hh = 0; hh < 6; ++hh) {
                acc[hh][0] += ev[hh] * pb.x; acc[hh][1] += ev[hh] * pb.y;
                acc[hh][2] += ev[hh] * pb.z; acc[hh][3] += ev[hh] * pb.w;
            }
        }
    }

    const size_t po = (size_t)bid * PART_STRIDE;
    __syncthreads();
    // bulk e2 write: one contiguous 12 KB chunk per block
    for (int idx = t; idx < 3072; idx += 256)
        e2[(size_t)bid * 3072 + idx] = l_s[(idx >> 8) * 260 + (idx & 255)];
    // s sums from l_s: per-wave 3 h (256 j = 4 strided reads per lane)
    #pragma unroll
    for (int k = 0; k < 3; ++k) {
        int h = wv * 3 + k;
        float sv = l_s[h * 260 + lane] + l_s[h * 260 + 64 + lane]
                 + l_s[h * 260 + 128 + lane] + l_s[h * 260 + 192 + lane];
        #pragma unroll
        for (int o = 32; o > 0; o >>= 1) sv += __shfl_xor(sv, o, 64);
        if (lane == 0) part[po + h] = sv;
    }

    // o_pair partial reduce over 4 wv, per h-half round; red overlays p_s
    __syncthreads();
    float* red = p_s;   // [4 wv][32 cg] stride 25 -> conflict-free
    #pragma unroll
    for (int round = 0; round < 2; ++round) {
        if (hg == round) {
            #pragma unroll
            for (int hh = 0; hh < 6; ++hh)
                #pragma unroll
                for (int u = 0; u < 4; ++u)
                    red[(wv * 32 + cg) * 25 + hh * 4 + u] = acc[hh][u];
        }
        __syncthreads();
        for (int idx = t; idx < 768; idx += 256) {
            int hh = idx >> 7, c = idx & 127;
            int cgg = c >> 2, uu = c & 3;
            float sv = red[(0 * 32 + cgg) * 25 + hh * 4 + uu]
                     + red[(1 * 32 + cgg) * 25 + hh * 4 + uu]
                     + red[(2 * 32 + cgg) * 25 + hh * 4 + uu]
                     + red[(3 * 32 + cgg) * 25 + hh * 4 + uu];
            part[po + 12 + (round * 6 + hh) * 128 + c] = sv;
        }
        __syncthreads();
    }
}

// ---------------------------------------------------------------------------
// K_FINISH: merges 2 chunk-partials; e held in REGISTERS per wave-head.
// e2 layout: per-256-j-chunk block-major [chunk][h*256+jl].
// ---------------------------------------------------------------------------
__global__ __launch_bounds__(256) void k_finish(
    const float* __restrict__ part, const float* __restrict__ e2,
    const float* __restrict__ vT, const float* __restrict__ vptsT,
    const float* __restrict__ t_rot, const float* __restrict__ t_trans,
    float* __restrict__ feats)
{
    __shared__ float inv_s[12];
    __shared__ __align__(16) float optg_s[288];
    __shared__ float R_s[9], T_s[3];
    __shared__ float red[480 * 17];
    const int row = blockIdx.x;
    const int b = row >> 9;
    const int t = threadIdx.x;
    const size_t pb = (size_t)row * 2 * PART_STRIDE;
    const size_t eb = (size_t)row * 2 * 3072;
    if (t < 12) {
        float sv = part[pb + t] + part[pb + PART_STRIDE + t];
        inv_s[t] = 1.0f / sv;
    }
    if (t < 9) R_s[t] = t_rot[(size_t)row * 9 + t];
    if (t < 3) T_s[t] = t_trans[(size_t)row * 3 + t];
    __syncthreads();

    size_t fb = (size_t)row * 2112;
    for (int idx = t; idx < 1536; idx += 256) {
        int h = idx >> 7;
        float sv = part[pb + 12 + idx] + part[pb + PART_STRIDE + 12 + idx];
        feats[fb + 576 + idx] = sv * inv_s[h];
    }

    const int wv = t >> 6, lane = t & 63;
    // e-rows for this wave's 3 heads -> registers
    float4 er[3][2];
    #pragma unroll
    for (int k = 0; k < 3; ++k) {
        int h = wv * 3 + k;
        int jq0 = lane, jq1 = lane + 64;   // float4 index in [0,128)
        er[k][0] = *(const float4*)&e2[eb + (size_t)(jq0 >> 6) * 3072 + h * 256 + (jq0 & 63) * 4];
        er[k][1] = *(const float4*)&e2[eb + (size_t)(jq1 >> 6) * 3072 + h * 256 + (jq1 & 63) * 4];
    }
    #pragma unroll
    for (int k = 0; k < 3; ++k) {
        int h = wv * 3 + k;
        const float* vbase  = vT + ((size_t)((b * 12 + h) * 16) << 9);
        const float* vpbase = vptsT + ((size_t)((b * 12 + h) * 24) << 9);
        for (int ol = 0; ol < 40; ++ol) {
            const float* src; int oi;
            if (ol < 16) { oi = h * 16 + ol;            src = vbase + (ol << 9); }
            else         { int pt = ol - 16; oi = 192 + h * 24 + pt; src = vpbase + (pt << 9); }
            const float4* s4 = (const float4*)src;
            float4 v0 = s4[lane], v1 = s4[lane + 64];
            float accv = er[k][0].x * v0.x + er[k][0].y * v0.y
                       + er[k][0].z * v0.z + er[k][0].w * v0.w
                       + er[k][1].x * v1.x + er[k][1].y * v1.y
                       + er[k][1].z * v1.z + er[k][1].w * v1.w;
            accv += __shfl_xor(accv, 1, 64);   // quad DPP
            accv += __shfl_xor(accv, 2, 64);   // quad DPP
            if ((lane & 3) == 0) red[oi * 17 + (lane >> 2)] = accv;
        }
    }
    __syncthreads();
    for (int idx = t; idx < 480; idx += 256) {
        int h = (idx < 192) ? (idx >> 4) : ((idx - 192) / 24);
        float sv = 0.f;
        #pragma unroll
        for (int q = 0; q < 16; ++q) sv += red[idx * 17 + q];
        sv *= inv_s[h];
        if (idx < 192) feats[fb + idx] = sv;
        else           optg_s[idx - 192] = sv;
    }
    __syncthreads();

    if (t < 96) {
        float gx = optg_s[t * 3 + 0] - T_s[0];
        float gy = optg_s[t * 3 + 1] - T_s[1];
        float gz = optg_s[t * 3 + 2] - T_s[2];
        float ox = R_s[0] * gx + R_s[3] * gy + R_s[6] * gz;
        float oy = R_s[1] * gx + R_s[4] * gy + R_s[7] * gz;
        float oz = R_s[2] * gx + R_s[5] * gy + R_s[8] * gz;
        float nrm = sqrtf(ox * ox + oy * oy + oz * oz + 1e-8f);
        feats[fb + 192 + t] = ox;
        feats[fb + 288 + t] = oy;
        feats[fb + 384 + t] = oz;
        feats[fb + 480 + t] = nrm;
    }
}

// ---------------------------------------------------------------------------
// K_GEMM: tiled f32 GEMM, 32r x 128c per block, 4x4/thread, split-K via z.
// A-source = sum of n_parts partials (stride 393216) [+abias] [relu].
// ---------------------------------------------------------------------------
__global__ __launch_bounds__(256) void k_gemm(
    const float* __restrict__ A0, int n_parts,
    const float* __restrict__ abias, int lda,
    const float* __restrict__ W,
    float* __restrict__ out, int k_chunks, int do_relu)
{
    __shared__ __align__(16) float A_t[64 * 36];
    __shared__ __align__(16) float W_s[64 * 132];
    const int row0 = blockIdx.x * 32;
    const int C0 = blockIdx.y * 128;
    const int k_base = blockIdx.z * k_chunks * 64;
    const int t = threadIdx.x;
    const int cq = t & 31, rq = t >> 5;
    float acc[4][4] = {};
    for (int ch = 0; ch < k_chunks; ++ch) {
        const int k0 = k_base + ch * 64;
        __syncthreads();
        for (int idx = t; idx < 512; idx += 256) {
            int r = idx & 31, kq = idx >> 5;
            float4 a = *(const float4*)&A0[(size_t)(row0 + r) * lda + k0 + kq * 4];
            for (int q = 1; q < n_parts; ++q) {
                float4 a1 = *(const float4*)&A0[(size_t)q * 393216 +
                                                (size_t)(row0 + r) * lda + k0 + kq * 4];
                a.x += a1.x; a.y += a1.y; a.z += a1.z; a.w += a1.w;
            }
            if (abias) {
                float4 ab = *(const float4*)&abias[k0 + kq * 4];
                a.x += ab.x; a.y += ab.y; a.z += ab.z; a.w += ab.w;
            }
            if (do_relu) {
                a.x = fmaxf(a.x, 0.f); a.y = fmaxf(a.y, 0.f);
                a.z = fmaxf(a.z, 0.f); a.w = fmaxf(a.w, 0.f);
            }
            A_t[(kq * 4 + 0) * 36 + r] = a.x;
            A_t[(kq * 4 + 1) * 36 + r] = a.y;
            A_t[(kq * 4 + 2) * 36 + r] = a.z;
            A_t[(kq * 4 + 3) * 36 + r] = a.w;
        }
        for (int idx = t; idx < 2048; idx += 256) {
            int kk = idx >> 5, c4 = idx & 31;
            *(float4*)&W_s[kk * 132 + c4 * 4] =
                *(const float4*)&W[(size_t)(k0 + kk) * 384 + C0 + c4 * 4];
        }
        __syncthreads();
        #pragma unroll 8
        for (int kk = 0; kk < 64; ++kk) {
            float4 a4 = *(const float4*)&A_t[kk * 36 + rq * 4];
            float4 w4 = *(const float4*)&W_s[kk * 132 + cq * 4];
            acc[0][0] += a4.x * w4.x; acc[0][1] += a4.x * w4.y; acc[0][2] += a4.x * w4.z; acc[0][3] += a4.x * w4.w;
            acc[1][0] += a4.y * w4.x; acc[1][1] += a4.y * w4.y; acc[1][2] += a4.y * w4.z; acc[1][3] += a4.y * w4.w;
            acc[2][0] += a4.z * w4.x; acc[2][1] += a4.z * w4.y; acc[2][2] += a4.z * w4.z; acc[2][3] += a4.z * w4.w;
            acc[3][0] += a4.w * w4.x; acc[3][1] += a4.w * w4.y; acc[3][2] += a4.w * w4.z; acc[3][3] += a4.w * w4.w;
        }
    }
    float* outp = out + (size_t)blockIdx.z * 393216;
    #pragma unroll
    for (int r = 0; r < 4; ++r) {
        float4 st = { acc[r][0], acc[r][1], acc[r][2], acc[r][3] };
        *(float4*)&outp[(size_t)(row0 + rq * 4 + r) * 384 + C0 + cq * 4] = st;
    }
}

// ---------------------------------------------------------------------------
// K_LNSUM: out = LN( sum(parts) + bias + resid ), one wave per row.
// If w_bb != null, also computes the fused backbone update.
// ---------------------------------------------------------------------------
__global__ __launch_bounds__(256) void k_lnsum(
    const float* __restrict__ parts, int np,
    const float* __restrict__ bias, const float* __restrict__ resid,
    const float* __restrict__ g, const float* __restrict__ bta,
    float* __restrict__ o,
    const float* __restrict__ w_bb, const float* __restrict__ b_bb,
    const float* __restrict__ t_rot, const float* __restrict__ t_trans,
    float* __restrict__ rot_out, float* __restrict__ trans_out)
{
    const int wid = (blockIdx.x * 256 + threadIdx.x) >> 6;
    const int lane = threadIdx.x & 63;
    float v[6], sum = 0.f, sq = 0.f;
    #pragma unroll
    for (int u = 0; u < 6; ++u) {
        int c = lane + 64 * u;
        float x = bias[c] + resid[(size_t)wid * 384 + c];
        for (int q = 0; q < np; ++q)
            x += parts[(size_t)q * 393216 + (size_t)wid * 384 + c];
        v[u] = x; sum += x; sq += x * x;
    }
    #pragma unroll
    for (int off = 32; off > 0; off >>= 1) {
        sum += __shfl_xor(sum, off, 64);
        sq  += __shfl_xor(sq, off, 64);
    }
    float mean = sum * (1.f / 384.f);
    float var = sq * (1.f / 384.f) - mean * mean;
    float rst = rsqrtf(var + 1e-5f);
    #pragma unroll
    for (int u = 0; u < 6; ++u) {
        int c = lane + 64 * u;
        v[u] = (v[u] - mean) * rst * g[c] + bta[c];
        o[(size_t)wid * 384 + c] = v[u];
    }
    if (!w_bb) return;

    float uacc[6] = {0.f, 0.f, 0.f, 0.f, 0.f, 0.f};
    #pragma unroll
    for (int u = 0; u < 6; ++u) {
        int c = lane + 64 * u;
        #pragma unroll
        for (int j = 0; j < 6; ++j) uacc[j] += v[u] * w_bb[c * 6 + j];
    }
    #pragma unroll
    for (int j = 0; j < 6; ++j) {
        #pragma unroll
        for (int off = 32; off > 0; off >>= 1) uacc[j] += __shfl_xor(uacc[j], off, 64);
    }
    if (lane == 0) {
        #pragma unroll
        for (int j = 0; j < 6; ++j) uacc[j] += b_bb[j];
        float bq = uacc[0], cq = uacc[1], dq = uacc[2];
        float inv = rsqrtf(1.f + bq * bq + cq * cq + dq * dq);
        float a = inv, bqn = bq * inv, cqn = cq * inv, dqn = dq * inv;
        float R[9];
        R[0] = a * a + bqn * bqn - cqn * cqn - dqn * dqn;
        R[1] = 2.f * (bqn * cqn - a * dqn);
        R[2] = 2.f * (bqn * dqn + a * cqn);
        R[3] = 2.f * (bqn * cqn + a * dqn);
        R[4] = a * a - bqn * bqn + cqn * cqn - dqn * dqn;
        R[5] = 2.f * (cqn * dqn - a * bqn);
        R[6] = 2.f * (bqn * dqn - a * cqn);
        R[7] = 2.f * (cqn * dqn + a * bqn);
        R[8] = a * a - bqn * bqn - cqn * cqn + dqn * dqn;
        const float* Rt = t_rot + (size_t)wid * 9;
        #pragma unroll
        for (int i2 = 0; i2 < 3; ++i2) {
            #pragma unroll
            for (int k2 = 0; k2 < 3; ++k2) {
                rot_out[(size_t)wid * 9 + i2 * 3 + k2] =
                    Rt[i2 * 3 + 0] * R[0 + k2] + Rt[i2 * 3 + 1] * R[3 + k2] + Rt[i2 * 3 + 2] * R[6 + k2];
            }
            trans_out[(size_t)wid * 3 + i2] =
                Rt[i2 * 3 + 0] * uacc[3] + Rt[i2 * 3 + 1] * uacc[4] + Rt[i2 * 3 + 2] * uacc[5]
                + t_trans[(size_t)wid * 3 + i2];
        }
    }
}

// ---------------------------------------------------------------------------
extern "C" void kernel_launch(void* const* d_in, const int* in_sizes, int n_in,
                              void* d_out, int out_size, void* d_ws, size_t ws_size,
                              hipStream_t stream) {
    const float* s      = (const float*)d_in[0];
    const float* p      = (const float*)d_in[1];
    const float* t_rot  = (const float*)d_in[2];
    const float* t_trans= (const float*)d_in[3];
    const float* mask   = (const float*)d_in[4];
    const float* wq     = (const float*)d_in[5];
    const float* bq     = (const float*)d_in[6];
    const float* wkv    = (const float*)d_in[7];
    const float* bkv    = (const float*)d_in[8];
    const float* wqp    = (const float*)d_in[9];
    const float* bqp    = (const float*)d_in[10];
    const float* wkvp   = (const float*)d_in[11];
    const float* bkvp   = (const float*)d_in[12];
    const float* wb     = (const float*)d_in[13];
    const float* bpb    = (const float*)d_in[14];
    const float* hwts   = (const float*)d_in[15];
    const float* w_out  = (const float*)d_in[16];
    const float* b_out  = (const float*)d_in[17];
    const float* ln1s   = (const float*)d_in[18];
    const float* ln1b   = (const float*)d_in[19];
    const float* wt1    = (const float*)d_in[20];
    const float* bt1    = (const float*)d_in[21];
    const float* wt2    = (const float*)d_in[22];
    const float* bt2    = (const float*)d_in[23];
    const float* wt3    = (const float*)d_in[24];
    const float* bt3    = (const float*)d_in[25];
    const float* ln2s   = (const float*)d_in[26];
    const float* ln2b   = (const float*)d_in[27];
    const float* w_bb   = (const float*)d_in[28];
    const float* b_bb   = (const float*)d_in[29];
    float* out = (float*)d_out;
    float* ws  = (float*)d_ws;

    float* q_o   = ws;                    // 196608
    float* kT2   = q_o   + 196608;        // 196608
    float* vT    = kT2   + 196608;        // 196608
    float* qpl   = vT    + 196608;        // 147456
    float* qpg   = qpl   + 147456;        // 147456
    float* kvpl  = qpg   + 147456;        // 442368
    float* kpT2  = kvpl  + 442368;        // 147456
    float* vptsT = kpT2  + 147456;        // 294912
    float* feats = vptsT + 294912;        // 2162688
    float* s1    = feats + 2162688;       // 393216
    float* e2    = s1    + 393216;        // 6291456: e2 (attn) -> gparts (out-proj)
    float* partb = e2    + 6291456;       // attn parts (3.3M) -> t1/t2/t3 partials
    float* partb2= partb + 2359296;       // second 6-partial region

    k_proj<<<dim3(32, 9), 256, 0, stream>>>(s, wq, bq, wkv, bkv, wqp, bqp, wkvp, bkvp,
                                            q_o, kT2, vT, qpl, kvpl);
    k_pts<<<1024, 192, 0, stream>>>(qpl, kvpl, t_rot, t_trans, qpg, kpT2, vptsT);
    k_attn1p<<<2048, 256, 0, stream>>>(q_o, kT2, qpg, kpT2, p, wb, bpb, hwts,
                                       mask, e2, partb);
    k_finish<<<1024, 256, 0, stream>>>(partb, e2, vT, vptsT, t_rot, t_trans, feats);
    // out-proj: split-K 11 x 192 (grid 1056). partials reuse e2 (dead).
    k_gemm<<<dim3(32, 3, 11), 256, 0, stream>>>(feats, 1, nullptr, 2112,
                                                w_out, e2, 3, 0);
    k_lnsum<<<256, 256, 0, stream>>>(e2, 11, b_out, s, ln1s, ln1b, s1,
                                     nullptr, nullptr, nullptr, nullptr,
                                     nullptr, nullptr);
    // transitions: split-K 6 x 64 each (grid 576); partial-sum+bias+relu fused
    // into the consumer's A-load (n_parts).
    k_gemm<<<dim3(32, 3, 6), 256, 0, stream>>>(s1, 1, nullptr, 384,
                                               wt1, partb, 1, 0);
    k_gemm<<<dim3(32, 3, 6), 256, 0, stream>>>(partb, 6, bt1, 384,
                                               wt2, partb2, 1, 1);
    k_gemm<<<dim3(32, 3, 6), 256, 0, stream>>>(partb2, 6, bt2, 384,
                                               wt3, partb, 1, 1);
    k_lnsum<<<256, 256, 0, stream>>>(partb, 6, bt3, s1, ln2s, ln2b, out,
                                     w_bb, b_bb, t_rot, t_trans,
                                     out + 393216, out + 402432);
}

// Round 19
// 362.959 us; speedup vs baseline: 1.2759x; 1.0155x over previous
//
#include <hip/hip_runtime.h>
#include <math.h>

#define QK_SCALE 0.14433756729740643f   // 1/sqrt(3*16)
#define BB_SCALE 0.57735026918962576f   // 1/sqrt(3)
#define HW_COEF  0.13608276348795434f   // 1/sqrt(54)

// part layout per (row,jc2), stride 1600 floats:
// [0:12] s_sum, [12:1548] o_pair partial (h*128+c)
#define PART_STRIDE 1600

// ---------------------------------------------------------------------------
// K_PROJ: tiled GEMM (1024x384)@(384x1152 composite) with scatter epilogue.
// ---------------------------------------------------------------------------
__global__ __launch_bounds__(256) void k_proj(
    const float* __restrict__ s,
    const float* __restrict__ wq,  const float* __restrict__ bq,
    const float* __restrict__ wkv, const float* __restrict__ bkv,
    const float* __restrict__ wqp, const float* __restrict__ bqp,
    const float* __restrict__ wkvp,const float* __restrict__ bkvp,
    float* __restrict__ q_o,    // (B,N,192)
    float* __restrict__ kT2,    // (B,12,512,16)
    float* __restrict__ vT,     // (B,12,16,512)
    float* __restrict__ qpl,    // (B,N,48,3) local
    float* __restrict__ kvpl)   // (B,N,144,3) local
{
    __shared__ __align__(16) float A_t[64 * 36];
    __shared__ __align__(16) float W_s[64 * 132];
    const int row0 = blockIdx.x * 32;
    const int C0 = blockIdx.y * 128;
    const int t = threadIdx.x;
    const int cq = t & 31, rq = t >> 5;
    float acc[4][4] = {};
    for (int ch = 0; ch < 6; ++ch) {
        const int k0 = ch * 64;
        __syncthreads();
        for (int idx = t; idx < 512; idx += 256) {
            int r = idx & 31, kq = idx >> 5;
            float4 a = *(const float4*)&s[(size_t)(row0 + r) * 384 + k0 + kq * 4];
            A_t[(kq * 4 + 0) * 36 + r] = a.x;
            A_t[(kq * 4 + 1) * 36 + r] = a.y;
            A_t[(kq * 4 + 2) * 36 + r] = a.z;
            A_t[(kq * 4 + 3) * 36 + r] = a.w;
        }
        for (int idx = t; idx < 2048; idx += 256) {
            int kk = idx >> 5, c4 = idx & 31;
            int C4 = C0 + c4 * 4;
            const float* w; int sub, wcols;
            if (C4 < 192)      { w = wq;   sub = C4;       wcols = 192; }
            else if (C4 < 576) { w = wkv;  sub = C4 - 192; wcols = 384; }
            else if (C4 < 720) { w = wqp;  sub = C4 - 576; wcols = 144; }
            else               { w = wkvp; sub = C4 - 720; wcols = 432; }
            *(float4*)&W_s[kk * 132 + c4 * 4] =
                *(const float4*)&w[(size_t)(k0 + kk) * wcols + sub];
        }
        __syncthreads();
        #pragma unroll 8
        for (int kk = 0; kk < 64; ++kk) {
            float4 a4 = *(const float4*)&A_t[kk * 36 + rq * 4];
            float4 w4 = *(const float4*)&W_s[kk * 132 + cq * 4];
            acc[0][0] += a4.x * w4.x; acc[0][1] += a4.x * w4.y; acc[0][2] += a4.x * w4.z; acc[0][3] += a4.x * w4.w;
            acc[1][0] += a4.y * w4.x; acc[1][1] += a4.y * w4.y; acc[1][2] += a4.y * w4.z; acc[1][3] += a4.y * w4.w;
            acc[2][0] += a4.z * w4.x; acc[2][1] += a4.z * w4.y; acc[2][2] += a4.z * w4.z; acc[2][3] += a4.z * w4.w;
            acc[3][0] += a4.w * w4.x; acc[3][1] += a4.w * w4.y; acc[3][2] += a4.w * w4.z; acc[3][3] += a4.w * w4.w;
        }
    }
    #pragma unroll
    for (int r = 0; r < 4; ++r) {
        int row = row0 + rq * 4 + r;
        int b = row >> 9, n = row & 511;
        #pragma unroll
        for (int u = 0; u < 4; ++u) {
            int col = C0 + cq * 4 + u;
            float v = acc[r][u];
            if (col < 192) {
                q_o[(size_t)row * 192 + col] = v + bq[col];
            } else if (col < 576) {
                int sub = col - 192;
                v += bkv[sub];
                int h = sub >> 5, rr = sub & 31;
                if (rr < 16) kT2[((size_t)((b * 12 + h) << 9) + n) * 16 + rr] = v;
                else         vT[(((b * 12 + h) * 16 + (rr - 16)) << 9) + n] = v;
            } else if (col < 720) {
                int sub = col - 576;
                v += bqp[sub];
                int axis = sub / 48, rem = sub % 48;
                qpl[(size_t)row * 144 + rem * 3 + axis] = v;
            } else {
                int sub = col - 720;
                v += bkvp[sub];
                int axis = sub / 144, rem = sub % 144;
                kvpl[(size_t)row * 432 + rem * 3 + axis] = v;
            }
        }
    }
}

// ---------------------------------------------------------------------------
// K_PTS: local->global point transform + scatter
// ---------------------------------------------------------------------------
__global__ __launch_bounds__(192) void k_pts(
    const float* __restrict__ qpl, const float* __restrict__ kvpl,
    const float* __restrict__ t_rot, const float* __restrict__ t_trans,
    float* __restrict__ qpg,    // (B,N,144)
    float* __restrict__ kpT2,   // (B,12,512,12)
    float* __restrict__ vptsT)  // (B,12,24,512)
{
    const int row = blockIdx.x;
    const int b = row >> 9, n = row & 511;
    const int t = threadIdx.x;
    __shared__ float R[9], T[3];
    if (t < 9) R[t] = t_rot[(size_t)row * 9 + t];
    if (t < 3) T[t] = t_trans[(size_t)row * 3 + t];
    __syncthreads();
    float lx, ly, lz;
    if (t < 48) {
        lx = qpl[(size_t)row * 144 + t * 3 + 0];
        ly = qpl[(size_t)row * 144 + t * 3 + 1];
        lz = qpl[(size_t)row * 144 + t * 3 + 2];
    } else {
        int pp = t - 48;
        lx = kvpl[(size_t)row * 432 + pp * 3 + 0];
        ly = kvpl[(size_t)row * 432 + pp * 3 + 1];
        lz = kvpl[(size_t)row * 432 + pp * 3 + 2];
    }
    float gx = R[0] * lx + R[1] * ly + R[2] * lz + T[0];
    float gy = R[3] * lx + R[4] * ly + R[5] * lz + T[1];
    float gz = R[6] * lx + R[7] * ly + R[8] * lz + T[2];
    if (t < 48) {
        qpg[(size_t)row * 144 + t * 3 + 0] = gx;
        qpg[(size_t)row * 144 + t * 3 + 1] = gy;
        qpg[(size_t)row * 144 + t * 3 + 2] = gz;
    } else {
        int pp = t - 48;
        int h = pp / 12, pt = pp % 12;
        if (pt < 4) {
            size_t base = ((size_t)((b * 12 + h) << 9) + n) * 12 + pt * 3;
            kpT2[base + 0] = gx; kpT2[base + 1] = gy; kpT2[base + 2] = gz;
        } else {
            int base = (((b * 12 + h) * 24 + (pt - 4) * 3) << 9) + n;
            vptsT[base] = gx; vptsT[base + 512] = gy; vptsT[base + 1024] = gz;
        }
    }
}

// ---------------------------------------------------------------------------
// K_ATTN1P (round-19): round-18 structure (256 j chunk, grid 2048) + T5
// s_setprio(1)/(0) around the o_pair FMA cluster. With 3 blocks/CU each at
// independent phases, boosting the compute-phase waves' priority lets them
// preempt other blocks' staging loads (guide T5: pays on phase-split
// schedules, null on lockstep). Everything else byte-identical to round-18.
// ---------------------------------------------------------------------------
__global__ __launch_bounds__(256) void k_attn1p(
    const float* __restrict__ q_o,   // (B,N,192)
    const float* __restrict__ kT2,   // (B,12,512,16)
    const float* __restrict__ qpg,   // (B,N,144)
    const float* __restrict__ kpT2,  // (B,12,512,12)
    const float* __restrict__ p,     // (B,N,N,128)
    const float* __restrict__ wb,    // (128,12)
    const float* __restrict__ bpb,   // (12)
    const float* __restrict__ hwts,  // (12)
    const float* __restrict__ mask,  // (B,N)
    float* __restrict__ e2,          // (2048, 3072) unnormalized exp, block-major
    float* __restrict__ part)        // (2048, 1600)
{
    __shared__ __align__(16) float p_s[32 * 132];   // 16.9 KB tile; final 'red'
    __shared__ __align__(16) float l_s[12 * 260];   // base logits -> e in place
    __shared__ float red_s[3360];                   // [j32:105][q:13][h] pwb partials
    __shared__ __align__(16) float e_sT[32 * 20];   // e transposed for o_pair
    __shared__ __align__(16) float q_s[192];
    __shared__ __align__(16) float qp_s[144];
    __shared__ float hw_s[12];
    __shared__ float misc_s[2];

    const int bid = blockIdx.x;
    const int row = bid >> 1, jc = bid & 1;
    const int b = row >> 9, i = row & 511;
    const int j0 = jc * 256;
    const int t = threadIdx.x;
    const int cg = t & 31;          // c-quad (pwb + o_pair)
    const int jg = t >> 5;          // j-group for staging/pwb (0..7)
    const int hg = (t >> 5) & 1;    // h-half for o_pair
    const int wv = t >> 6;          // wave index
    const int lane = t & 63;

    const float* psrc = p + ((size_t)(b * 512 + i) * 512 + j0) * 128;
    const float4* p4 = (const float4*)psrc;  // 8192 f4 (256 j x 32 cq)

    for (int idx = t; idx < 192; idx += 256) q_s[idx] = q_o[(size_t)row * 192 + idx];
    for (int idx = t; idx < 144; idx += 256) qp_s[idx] = qpg[(size_t)row * 144 + idx];
    if (t < 12) {
        float x = hwts[t];
        float sp = (x > 20.f) ? x : log1pf(__expf(x));
        hw_s[t] = sp * HW_COEF;
    }
    if (t == 0) misc_s[0] = mask[row];

    // wb -> registers: this thread's 4 c x 12 h (one-time scattered loads)
    float wbr[4][12];
    #pragma unroll
    for (int cu = 0; cu < 4; ++cu)
        #pragma unroll
        for (int h = 0; h < 12; ++h)
            wbr[cu][h] = wb[(cg * 4 + cu) * 12 + h];

    // prefetch tile 0 (32 j): thread covers (j = jg + 8u, cq = cg)
    float4 rv[4];
    #pragma unroll
    for (int u = 0; u < 4; ++u) rv[u] = p4[t + 256 * u];

    __syncthreads();
    const float mi = misc_s[0];

    // phase 1: base logits for all 256 j (hides tile-0 load latency)
    {
        const float4* q4 = (const float4*)q_s;
        const float4* qp4 = (const float4*)qp_s;
        for (int idx = t; idx < 3072; idx += 256) {
            int h = idx >> 8, jl = idx & 255;
            int j = j0 + jl;
            const float4* k4 = (const float4*)&kT2[((size_t)((b * 12 + h) << 9) + j) * 16];
            float qk = 0.f;
            #pragma unroll
            for (int c4 = 0; c4 < 4; ++c4) {
                float4 qv = q4[h * 4 + c4], kv = k4[c4];
                qk += qv.x * kv.x + qv.y * kv.y + qv.z * kv.z + qv.w * kv.w;
            }
            const float4* kp4 = (const float4*)&kpT2[((size_t)((b * 12 + h) << 9) + j) * 12];
            float d2 = 0.f;
            #pragma unroll
            for (int x = 0; x < 3; ++x) {
                float4 qp = qp4[h * 3 + x], kp = kp4[x];
                float dx = qp.x - kp.x, dy = qp.y - kp.y;
                float dz = qp.z - kp.z, dw = qp.w - kp.w;
                d2 += dx * dx + dy * dy + dz * dz + dw * dw;
            }
            float mj = mask[b * 512 + j];
            l_s[h * 260 + jl] = QK_SCALE * qk - 0.5f * hw_s[h] * d2
                                + BB_SCALE * bpb[h] + 100000.0f * (mi * mj - 1.0f);
        }
    }

    float acc[6][4] = {};
    const int hsub = cg & 3, qq = cg >> 2;

    for (int tile = 0; tile < 8; ++tile) {
        __syncthreads();                     // p_s, red_s, e_sT reusable
        // stage tile to LDS + pwb partials from the SAME registers
        #pragma unroll
        for (int u = 0; u < 4; ++u) {
            int j32 = jg + 8 * u;
            *(float4*)&p_s[j32 * 132 + cg * 4] = rv[u];
            float partial[12];
            #pragma unroll
            for (int h = 0; h < 12; ++h)
                partial[h] = rv[u].x * wbr[0][h] + rv[u].y * wbr[1][h]
                           + rv[u].z * wbr[2][h] + rv[u].w * wbr[3][h];
            #pragma unroll
            for (int h = 0; h < 12; ++h) {
                partial[h] += __shfl_xor(partial[h], 1, 64);   // quad DPP
                partial[h] += __shfl_xor(partial[h], 2, 64);   // quad DPP
            }
            // all lanes hold the quad sum; lane writes its 3-h slice (j-major)
            #pragma unroll
            for (int k = 0; k < 3; ++k)
                red_s[j32 * 105 + qq * 13 + hsub * 3 + k] = partial[hsub * 3 + k];
        }
        __syncthreads();                     // p_s + red_s ready
        if (tile < 7) {
            #pragma unroll
            for (int u = 0; u < 4; ++u)
                rv[u] = p4[(tile + 1) * 1024 + t + 256 * u];
        }
        // e-phase: gather 8 q-partials per (j,h); e -> l_s + e_sT
        for (int idx = t; idx < 384; idx += 256) {
            int h = idx >> 5, j32 = idx & 31;
            float pwb = 0.f;
            #pragma unroll
            for (int q = 0; q < 8; ++q) pwb += red_s[j32 * 105 + q * 13 + h];
            int jl = tile * 32 + j32;
            float e = __expf(l_s[h * 260 + jl] + BB_SCALE * pwb);
            l_s[h * 260 + jl] = e;
            e_sT[j32 * 20 + h + 2 * (h >= 6)] = e;
        }
        __syncthreads();                     // e visible
        // o_pair accumulate: pure FMA cluster — T5 priority boost
        __builtin_amdgcn_s_setprio(1);
        #pragma unroll
        for (int uu = 0; uu < 8; ++uu) {
            int jt = wv * 8 + uu;
            float4 pb = *(const float4*)&p_s[jt * 132 + cg * 4];
            float4 ea = *(const float4*)&e_sT[jt * 20 + hg * 8];
            float2 eb = *(const float2*)&e_sT[jt * 20 + hg * 8 + 4];
            float ev[6] = {ea.x, ea.y, ea.z, ea.w, eb.x, eb.y};
            #pragma unroll
            for (int hh = 0; hh < 6; ++hh) {
                acc[hh][0] += ev[hh] * pb.x; acc[hh][1] += ev[hh] * pb.y;
                acc[hh][2] += ev[hh] * pb.z; acc[hh][3] += ev[hh] * pb.w;
            }
        }
        __builtin_amdgcn_s_setprio(0);
    }

    const size_t po = (size_t)bid * PART_STRIDE;
    __syncthreads();
    // bulk e2 write: one contiguous 12 KB chunk per block
    for (int idx = t; idx < 3072; idx += 256)
        e2[(size_t)bid * 3072 + idx] = l_s[(idx >> 8) * 260 + (idx & 255)];
    // s sums from l_s: per-wave 3 h (256 j = 4 strided reads per lane)
    #pragma unroll
    for (int k = 0; k < 3; ++k) {
        int h = wv * 3 + k;
        float sv = l_s[h * 260 + lane] + l_s[h * 260 + 64 + lane]
                 + l_s[h * 260 + 128 + lane] + l_s[h * 260 + 192 + lane];
        #pragma unroll
        for (int o = 32; o > 0; o >>= 1) sv += __shfl_xor(sv, o, 64);
        if (lane == 0) part[po + h] = sv;
    }

    // o_pair partial reduce over 4 wv, per h-half round; red overlays p_s
    __syncthreads();
    float* red = p_s;   // [4 wv][32 cg] stride 25 -> conflict-free
    #pragma unroll
    for (int round = 0; round < 2; ++round) {
        if (hg == round) {
            #pragma unroll
            for (int hh = 0; hh < 6; ++hh)
                #pragma unroll
                for (int u = 0; u < 4; ++u)
                    red[(wv * 32 + cg) * 25 + hh * 4 + u] = acc[hh][u];
        }
        __syncthreads();
        for (int idx = t; idx < 768; idx += 256) {
            int hh = idx >> 7, c = idx & 127;
            int cgg = c >> 2, uu = c & 3;
            float sv = red[(0 * 32 + cgg) * 25 + hh * 4 + uu]
                     + red[(1 * 32 + cgg) * 25 + hh * 4 + uu]
                     + red[(2 * 32 + cgg) * 25 + hh * 4 + uu]
                     + red[(3 * 32 + cgg) * 25 + hh * 4 + uu];
            part[po + 12 + (round * 6 + hh) * 128 + c] = sv;
        }
        __syncthreads();
    }
}

// ---------------------------------------------------------------------------
// K_FINISH: merges 2 chunk-partials; e held in REGISTERS per wave-head.
// e2 layout: per-256-j-chunk block-major [chunk][h*256+jl].
// ---------------------------------------------------------------------------
__global__ __launch_bounds__(256) void k_finish(
    const float* __restrict__ part, const float* __restrict__ e2,
    const float* __restrict__ vT, const float* __restrict__ vptsT,
    const float* __restrict__ t_rot, const float* __restrict__ t_trans,
    float* __restrict__ feats)
{
    __shared__ float inv_s[12];
    __shared__ __align__(16) float optg_s[288];
    __shared__ float R_s[9], T_s[3];
    __shared__ float red[480 * 17];
    const int row = blockIdx.x;
    const int b = row >> 9;
    const int t = threadIdx.x;
    const size_t pb = (size_t)row * 2 * PART_STRIDE;
    const size_t eb = (size_t)row * 2 * 3072;
    if (t < 12) {
        float sv = part[pb + t] + part[pb + PART_STRIDE + t];
        inv_s[t] = 1.0f / sv;
    }
    if (t < 9) R_s[t] = t_rot[(size_t)row * 9 + t];
    if (t < 3) T_s[t] = t_trans[(size_t)row * 3 + t];
    __syncthreads();

    size_t fb = (size_t)row * 2112;
    for (int idx = t; idx < 1536; idx += 256) {
        int h = idx >> 7;
        float sv = part[pb + 12 + idx] + part[pb + PART_STRIDE + 12 + idx];
        feats[fb + 576 + idx] = sv * inv_s[h];
    }

    const int wv = t >> 6, lane = t & 63;
    // e-rows for this wave's 3 heads -> registers
    float4 er[3][2];
    #pragma unroll
    for (int k = 0; k < 3; ++k) {
        int h = wv * 3 + k;
        int jq0 = lane, jq1 = lane + 64;   // float4 index in [0,128)
        er[k][0] = *(const float4*)&e2[eb + (size_t)(jq0 >> 6) * 3072 + h * 256 + (jq0 & 63) * 4];
        er[k][1] = *(const float4*)&e2[eb + (size_t)(jq1 >> 6) * 3072 + h * 256 + (jq1 & 63) * 4];
    }
    #pragma unroll
    for (int k = 0; k < 3; ++k) {
        int h = wv * 3 + k;
        const float* vbase  = vT + ((size_t)((b * 12 + h) * 16) << 9);
        const float* vpbase = vptsT + ((size_t)((b * 12 + h) * 24) << 9);
        for (int ol = 0; ol < 40; ++ol) {
            const float* src; int oi;
            if (ol < 16) { oi = h * 16 + ol;            src = vbase + (ol << 9); }
            else         { int pt = ol - 16; oi = 192 + h * 24 + pt; src = vpbase + (pt << 9); }
            const float4* s4 = (const float4*)src;
            float4 v0 = s4[lane], v1 = s4[lane + 64];
            float accv = er[k][0].x * v0.x + er[k][0].y * v0.y
                       + er[k][0].z * v0.z + er[k][0].w * v0.w
                       + er[k][1].x * v1.x + er[k][1].y * v1.y
                       + er[k][1].z * v1.z + er[k][1].w * v1.w;
            accv += __shfl_xor(accv, 1, 64);   // quad DPP
            accv += __shfl_xor(accv, 2, 64);   // quad DPP
            if ((lane & 3) == 0) red[oi * 17 + (lane >> 2)] = accv;
        }
    }
    __syncthreads();
    for (int idx = t; idx < 480; idx += 256) {
        int h = (idx < 192) ? (idx >> 4) : ((idx - 192) / 24);
        float sv = 0.f;
        #pragma unroll
        for (int q = 0; q < 16; ++q) sv += red[idx * 17 + q];
        sv *= inv_s[h];
        if (idx < 192) feats[fb + idx] = sv;
        else           optg_s[idx - 192] = sv;
    }
    __syncthreads();

    if (t < 96) {
        float gx = optg_s[t * 3 + 0] - T_s[0];
        float gy = optg_s[t * 3 + 1] - T_s[1];
        float gz = optg_s[t * 3 + 2] - T_s[2];
        float ox = R_s[0] * gx + R_s[3] * gy + R_s[6] * gz;
        float oy = R_s[1] * gx + R_s[4] * gy + R_s[7] * gz;
        float oz = R_s[2] * gx + R_s[5] * gy + R_s[8] * gz;
        float nrm = sqrtf(ox * ox + oy * oy + oz * oz + 1e-8f);
        feats[fb + 192 + t] = ox;
        feats[fb + 288 + t] = oy;
        feats[fb + 384 + t] = oz;
        feats[fb + 480 + t] = nrm;
    }
}

// ---------------------------------------------------------------------------
// K_GEMM: tiled f32 GEMM, 32r x 128c per block, 4x4/thread, split-K via z.
// A-source = sum of n_parts partials (stride 393216) [+abias] [relu].
// ---------------------------------------------------------------------------
__global__ __launch_bounds__(256) void k_gemm(
    const float* __restrict__ A0, int n_parts,
    const float* __restrict__ abias, int lda,
    const float* __restrict__ W,
    float* __restrict__ out, int k_chunks, int do_relu)
{
    __shared__ __align__(16) float A_t[64 * 36];
    __shared__ __align__(16) float W_s[64 * 132];
    const int row0 = blockIdx.x * 32;
    const int C0 = blockIdx.y * 128;
    const int k_base = blockIdx.z * k_chunks * 64;
    const int t = threadIdx.x;
    const int cq = t & 31, rq = t >> 5;
    float acc[4][4] = {};
    for (int ch = 0; ch < k_chunks; ++ch) {
        const int k0 = k_base + ch * 64;
        __syncthreads();
        for (int idx = t; idx < 512; idx += 256) {
            int r = idx & 31, kq = idx >> 5;
            float4 a = *(const float4*)&A0[(size_t)(row0 + r) * lda + k0 + kq * 4];
            for (int q = 1; q < n_parts; ++q) {
                float4 a1 = *(const float4*)&A0[(size_t)q * 393216 +
                                                (size_t)(row0 + r) * lda + k0 + kq * 4];
                a.x += a1.x; a.y += a1.y; a.z += a1.z; a.w += a1.w;
            }
            if (abias) {
                float4 ab = *(const float4*)&abias[k0 + kq * 4];
                a.x += ab.x; a.y += ab.y; a.z += ab.z; a.w += ab.w;
            }
            if (do_relu) {
                a.x = fmaxf(a.x, 0.f); a.y = fmaxf(a.y, 0.f);
                a.z = fmaxf(a.z, 0.f); a.w = fmaxf(a.w, 0.f);
            }
            A_t[(kq * 4 + 0) * 36 + r] = a.x;
            A_t[(kq * 4 + 1) * 36 + r] = a.y;
            A_t[(kq * 4 + 2) * 36 + r] = a.z;
            A_t[(kq * 4 + 3) * 36 + r] = a.w;
        }
        for (int idx = t; idx < 2048; idx += 256) {
            int kk = idx >> 5, c4 = idx & 31;
            *(float4*)&W_s[kk * 132 + c4 * 4] =
                *(const float4*)&W[(size_t)(k0 + kk) * 384 + C0 + c4 * 4];
        }
        __syncthreads();
        #pragma unroll 8
        for (int kk = 0; kk < 64; ++kk) {
            float4 a4 = *(const float4*)&A_t[kk * 36 + rq * 4];
            float4 w4 = *(const float4*)&W_s[kk * 132 + cq * 4];
            acc[0][0] += a4.x * w4.x; acc[0][1] += a4.x * w4.y; acc[0][2] += a4.x * w4.z; acc[0][3] += a4.x * w4.w;
            acc[1][0] += a4.y * w4.x; acc[1][1] += a4.y * w4.y; acc[1][2] += a4.y * w4.z; acc[1][3] += a4.y * w4.w;
            acc[2][0] += a4.z * w4.x; acc[2][1] += a4.z * w4.y; acc[2][2] += a4.z * w4.z; acc[2][3] += a4.z * w4.w;
            acc[3][0] += a4.w * w4.x; acc[3][1] += a4.w * w4.y; acc[3][2] += a4.w * w4.z; acc[3][3] += a4.w * w4.w;
        }
    }
    float* outp = out + (size_t)blockIdx.z * 393216;
    #pragma unroll
    for (int r = 0; r < 4; ++r) {
        float4 st = { acc[r][0], acc[r][1], acc[r][2], acc[r][3] };
        *(float4*)&outp[(size_t)(row0 + rq * 4 + r) * 384 + C0 + cq * 4] = st;
    }
}

// ---------------------------------------------------------------------------
// K_LNSUM: out = LN( sum(parts) + bias + resid ), one wave per row.
// If w_bb != null, also computes the fused backbone update.
// ---------------------------------------------------------------------------
__global__ __launch_bounds__(256) void k_lnsum(
    const float* __restrict__ parts, int np,
    const float* __restrict__ bias, const float* __restrict__ resid,
    const float* __restrict__ g, const float* __restrict__ bta,
    float* __restrict__ o,
    const float* __restrict__ w_bb, const float* __restrict__ b_bb,
    const float* __restrict__ t_rot, const float* __restrict__ t_trans,
    float* __restrict__ rot_out, float* __restrict__ trans_out)
{
    const int wid = (blockIdx.x * 256 + threadIdx.x) >> 6;
    const int lane = threadIdx.x & 63;
    float v[6], sum = 0.f, sq = 0.f;
    #pragma unroll
    for (int u = 0; u < 6; ++u) {
        int c = lane + 64 * u;
        float x = bias[c] + resid[(size_t)wid * 384 + c];
        for (int q = 0; q < np; ++q)
            x += parts[(size_t)q * 393216 + (size_t)wid * 384 + c];
        v[u] = x; sum += x; sq += x * x;
    }
    #pragma unroll
    for (int off = 32; off > 0; off >>= 1) {
        sum += __shfl_xor(sum, off, 64);
        sq  += __shfl_xor(sq, off, 64);
    }
    float mean = sum * (1.f / 384.f);
    float var = sq * (1.f / 384.f) - mean * mean;
    float rst = rsqrtf(var + 1e-5f);
    #pragma unroll
    for (int u = 0; u < 6; ++u) {
        int c = lane + 64 * u;
        v[u] = (v[u] - mean) * rst * g[c] + bta[c];
        o[(size_t)wid * 384 + c] = v[u];
    }
    if (!w_bb) return;

    float uacc[6] = {0.f, 0.f, 0.f, 0.f, 0.f, 0.f};
    #pragma unroll
    for (int u = 0; u < 6; ++u) {
        int c = lane + 64 * u;
        #pragma unroll
        for (int j = 0; j < 6; ++j) uacc[j] += v[u] * w_bb[c * 6 + j];
    }
    #pragma unroll
    for (int j = 0; j < 6; ++j) {
        #pragma unroll
        for (int off = 32; off > 0; off >>= 1) uacc[j] += __shfl_xor(uacc[j], off, 64);
    }
    if (lane == 0) {
        #pragma unroll
        for (int j = 0; j < 6; ++j) uacc[j] += b_bb[j];
        float bq = uacc[0], cq = uacc[1], dq = uacc[2];
        float inv = rsqrtf(1.f + bq * bq + cq * cq + dq * dq);
        float a = inv, bqn = bq * inv, cqn = cq * inv, dqn = dq * inv;
        float R[9];
        R[0] = a * a + bqn * bqn - cqn * cqn - dqn * dqn;
        R[1] = 2.f * (bqn * cqn - a * dqn);
        R[2] = 2.f * (bqn * dqn + a * cqn);
        R[3] = 2.f * (bqn * cqn + a * dqn);
        R[4] = a * a - bqn * bqn + cqn * cqn - dqn * dqn;
        R[5] = 2.f * (cqn * dqn - a * bqn);
        R[6] = 2.f * (bqn * dqn - a * cqn);
        R[7] = 2.f * (cqn * dqn + a * bqn);
        R[8] = a * a - bqn * bqn - cqn * cqn + dqn * dqn;
        const float* Rt = t_rot + (size_t)wid * 9;
        #pragma unroll
        for (int i2 = 0; i2 < 3; ++i2) {
            #pragma unroll
            for (int k2 = 0; k2 < 3; ++k2) {
                rot_out[(size_t)wid * 9 + i2 * 3 + k2] =
                    Rt[i2 * 3 + 0] * R[0 + k2] + Rt[i2 * 3 + 1] * R[3 + k2] + Rt[i2 * 3 + 2] * R[6 + k2];
            }
            trans_out[(size_t)wid * 3 + i2] =
                Rt[i2 * 3 + 0] * uacc[3] + Rt[i2 * 3 + 1] * uacc[4] + Rt[i2 * 3 + 2] * uacc[5]
                + t_trans[(size_t)wid * 3 + i2];
        }
    }
}

// ---------------------------------------------------------------------------
extern "C" void kernel_launch(void* const* d_in, const int* in_sizes, int n_in,
                              void* d_out, int out_size, void* d_ws, size_t ws_size,
                              hipStream_t stream) {
    const float* s      = (const float*)d_in[0];
    const float* p      = (const float*)d_in[1];
    const float* t_rot  = (const float*)d_in[2];
    const float* t_trans= (const float*)d_in[3];
    const float* mask   = (const float*)d_in[4];
    const float* wq     = (const float*)d_in[5];
    const float* bq     = (const float*)d_in[6];
    const float* wkv    = (const float*)d_in[7];
    const float* bkv    = (const float*)d_in[8];
    const float* wqp    = (const float*)d_in[9];
    const float* bqp    = (const float*)d_in[10];
    const float* wkvp   = (const float*)d_in[11];
    const float* bkvp   = (const float*)d_in[12];
    const float* wb     = (const float*)d_in[13];
    const float* bpb    = (const float*)d_in[14];
    const float* hwts   = (const float*)d_in[15];
    const float* w_out  = (const float*)d_in[16];
    const float* b_out  = (const float*)d_in[17];
    const float* ln1s   = (const float*)d_in[18];
    const float* ln1b   = (const float*)d_in[19];
    const float* wt1    = (const float*)d_in[20];
    const float* bt1    = (const float*)d_in[21];
    const float* wt2    = (const float*)d_in[22];
    const float* bt2    = (const float*)d_in[23];
    const float* wt3    = (const float*)d_in[24];
    const float* bt3    = (const float*)d_in[25];
    const float* ln2s   = (const float*)d_in[26];
    const float* ln2b   = (const float*)d_in[27];
    const float* w_bb   = (const float*)d_in[28];
    const float* b_bb   = (const float*)d_in[29];
    float* out = (float*)d_out;
    float* ws  = (float*)d_ws;

    float* q_o   = ws;                    // 196608
    float* kT2   = q_o   + 196608;        // 196608
    float* vT    = kT2   + 196608;        // 196608
    float* qpl   = vT    + 196608;        // 147456
    float* qpg   = qpl   + 147456;        // 147456
    float* kvpl  = qpg   + 147456;        // 442368
    float* kpT2  = kvpl  + 442368;        // 147456
    float* vptsT = kpT2  + 147456;        // 294912
    float* feats = vptsT + 294912;        // 2162688
    float* s1    = feats + 2162688;       // 393216
    float* e2    = s1    + 393216;        // 6291456: e2 (attn) -> gparts (out-proj)
    float* partb = e2    + 6291456;       // attn parts (3.3M) -> t1/t2/t3 partials
    float* partb2= partb + 2359296;       // second 6-partial region

    k_proj<<<dim3(32, 9), 256, 0, stream>>>(s, wq, bq, wkv, bkv, wqp, bqp, wkvp, bkvp,
                                            q_o, kT2, vT, qpl, kvpl);
    k_pts<<<1024, 192, 0, stream>>>(qpl, kvpl, t_rot, t_trans, qpg, kpT2, vptsT);
    k_attn1p<<<2048, 256, 0, stream>>>(q_o, kT2, qpg, kpT2, p, wb, bpb, hwts,
                                       mask, e2, partb);
    k_finish<<<1024, 256, 0, stream>>>(partb, e2, vT, vptsT, t_rot, t_trans, feats);
    // out-proj: split-K 11 x 192 (grid 1056). partials reuse e2 (dead).
    k_gemm<<<dim3(32, 3, 11), 256, 0, stream>>>(feats, 1, nullptr, 2112,
                                                w_out, e2, 3, 0);
    k_lnsum<<<256, 256, 0, stream>>>(e2, 11, b_out, s, ln1s, ln1b, s1,
                                     nullptr, nullptr, nullptr, nullptr,
                                     nullptr, nullptr);
    // transitions: split-K 6 x 64 each (grid 576); partial-sum+bias+relu fused
    // into the consumer's A-load (n_parts).
    k_gemm<<<dim3(32, 3, 6), 256, 0, stream>>>(s1, 1, nullptr, 384,
                                               wt1, partb, 1, 0);
    k_gemm<<<dim3(32, 3, 6), 256, 0, stream>>>(partb, 6, bt1, 384,
                                               wt2, partb2, 1, 1);
    k_gemm<<<dim3(32, 3, 6), 256, 0, stream>>>(partb2, 6, bt2, 384,
                                               wt3, partb, 1, 1);
    k_lnsum<<<256, 256, 0, stream>>>(partb, 6, bt3, s1, ln2s, ln2b, out,
                                     w_bb, b_bb, t_rot, t_trans,
                                     out + 393216, out + 402432);
}